// Round 12
// baseline (149.256 us; speedup 1.0000x reference)
//
#include <hip/hip_runtime.h>
#include <stdint.h>

// ---------------------------------------------------------------------------
// MultiHeadSelfAttention: x(2,2048,1024) fp32, w_qkv(1024,3072), w_out(1024,1024)
// R11: QKV GEMM ported to the 256^2 8-phase template (m201): 512 thr / 8 waves
// (2Mx4N), BK=64, LDS 128KiB (2dbuf x 2half x 128x64 x {A,B}), 4 phases/tile,
// counted vmcnt(4) once per tile, T2 chunk-swizzle (chunk ^= row&7, pre-swizzled
// global source + XOR on read), T5 setprio around MFMA quadrants, T1 XCD swizzle
// (192%8==0 -> bijective). Out-proj stays on the 128^2 kernel (grid coverage).
// Attn: reverted to R9 single-pass (split-k + combine was net-negative).
// ---------------------------------------------------------------------------

#define B_ 2
#define T_ 2048
#define C_ 1024
#define H_ 16
#define D_ 64
#define F_ 3072
#define M_ 4096

typedef unsigned short u16;
typedef unsigned int u32;
typedef u16 u16x2 __attribute__((ext_vector_type(2)));
typedef u16 u16x4 __attribute__((ext_vector_type(4)));
typedef u16 u16x8 __attribute__((ext_vector_type(8)));
typedef __bf16 bf16x8 __attribute__((ext_vector_type(8)));
typedef float f32x4 __attribute__((ext_vector_type(4)));

#define AS1 __attribute__((address_space(1)))
#define AS3 __attribute__((address_space(3)))

__device__ __forceinline__ float b2f(u16 u) {
  union { unsigned int i; float f; } v; v.i = ((unsigned int)u) << 16; return v.f;
}
__device__ __forceinline__ u16 f2b(float f) {  // RNE, finite inputs
  unsigned int u = __float_as_uint(f);
  u += 0x7fffu + ((u >> 16) & 1u);
  return (u16)(u >> 16);
}
__device__ __forceinline__ bf16x8 u2b8(u16x8 v) {
  union { u16x8 u; bf16x8 b; } x; x.u = v; return x.b;
}

// --------------------------- small prep kernels ----------------------------

// interleaved {cos,sin} table: csT[t*32+i] = {cos(t*f_i), sin(t*f_i)}
__global__ __launch_bounds__(256) void rope_table_kernel(float2* csT) {
  int idx = blockIdx.x * 256 + threadIdx.x;    // T_*32 = 65536 threads
  int t = idx >> 5, i = idx & 31;
  float inv_freq = powf(10000.0f, -(float)(2 * i) / 64.0f);
  float ang = (float)t * inv_freq;
  csT[idx] = make_float2(cosf(ang), sinf(ang));
}

__global__ __launch_bounds__(256) void cast_x_kernel(const float* __restrict__ x,
                                                     u16* __restrict__ xb) {
  int i = blockIdx.x * 256 + threadIdx.x;      // M_*C_/4 threads
  float4 v = ((const float4*)x)[i];
  u16x4 r;
  r[0] = f2b(v.x); r[1] = f2b(v.y); r[2] = f2b(v.z); r[3] = f2b(v.w);
  ((u16x4*)xb)[i] = r;
}

// out[c][r] = bf16(in[r][c]);  R rows, Ccol cols in input. 32x32 tiles.
__global__ __launch_bounds__(256) void transpose_cast_kernel(const float* __restrict__ in,
                                                             u16* __restrict__ out,
                                                             int R, int Ccol) {
  __shared__ float tile[32][33];
  int c0 = blockIdx.x * 32, r0 = blockIdx.y * 32;
  int tx = threadIdx.x & 31, ty = threadIdx.x >> 5;   // ty = 0..7
  #pragma unroll
  for (int i = 0; i < 32; i += 8)
    tile[ty + i][tx] = in[(size_t)(r0 + ty + i) * Ccol + c0 + tx];
  __syncthreads();
  #pragma unroll
  for (int i = 0; i < 32; i += 8)
    out[(size_t)(c0 + ty + i) * R + r0 + tx] = f2b(tile[tx][ty + i]);
}

// ------------------- 256^2 8-phase QKV GEMM + RoPE epilogue ----------------
// C[4096,3072] = xb[4096,1024] x wqkvT[3072,1024]^T. 8 waves (wr=wv>>2 in
// {0,1}: M-half; wc=wv&3: N-quarter). Per wave: 128x64 out = 8x4 16x16 frags.
// 16 K-tiles BK=64; per tile 4 phases:
//  ph1: rd A[m0-3]x2ks (8) + B[n0-1]x2ks (4); stage A-h0(t+1); bar; Q0; bar
//  ph2: rd B[n2-3]x2ks (4);                  stage A-h1(t+1); bar; Q1; bar
//  ph3: rd A[m4-7]x2ks (8);                  stage B-h0(t+2); bar; Q2; bar
//  ph4: -;                  stage B-h1(t+2); vmcnt(4|0); bar; Q3; bar
// DMA-region audit: A(t+1)->sA[buf^1] last read in tile t-1 (done);
// B(t+2)->sB[buf] B-regions last read t.ph1/ph2 (done by ph2-end barrier).
// vmcnt(4)@ph4 retires everything except the 2 B-stages of ph3/ph4 -> tile
// t+1's A+B all landed before its ph1 reads (post-barrier). Prologue stages
// A(0)h0,h1 B(0)h0,h1 B(1)h0,h1 then vmcnt(4)+bar. Swizzle: LDS slot (r,c)
// holds global chunk c^(r&7); read chunk (ks*4+lq)^(l16&7) [both-sides rule].
__global__ __launch_bounds__(512, 2) void gemm256_qkv_kernel(
    const u16* __restrict__ A, const u16* __restrict__ Bt,
    u16* __restrict__ qr, u16* __restrict__ kr, u16* __restrict__ vrp,
    const float2* __restrict__ csT) {
  __shared__ u16 sA[2][2][8192];   // [dbuf][half][128*64]
  __shared__ u16 sB[2][2][8192];

  const int tid = threadIdx.x;
  const int lane = tid & 63;
  const int wv = tid >> 6;
  const int wr = wv >> 2, wc = wv & 3;
  const int l16 = lane & 15, lq = lane >> 4;

  // T1 XCD swizzle (192 blocks, 192%8==0 -> bijective)
  const int flat = blockIdx.y * 12 + blockIdx.x;
  const int swz = (flat & 7) * 24 + (flat >> 3);
  const int bx = swz % 12, by = swz / 12;
  const int rowBase = by * 256;
  const int colBase = bx * 256;

  // staging maps: per half-tile stage, lane covers row l*64 + wv*8 + (lane>>3),
  // slot chunk lane&7; source chunk pre-swizzled (^ row&7)
  const int lr8 = lane >> 3;
  const int schunk = ((lane & 7) ^ (lr8 & 7)) * 8;

#define STG_A(buf, half, kt)                                                     \
  {                                                                              \
    _Pragma("unroll")                                                            \
    for (int l = 0; l < 2; ++l)                                                  \
      __builtin_amdgcn_global_load_lds(                                          \
          (const AS1 u32*)(A + (size_t)(rowBase + (half) * 128 + l * 64 + wv * 8 + lr8) * 1024 + (kt) * 64 + schunk), \
          (AS3 u32*)&sA[buf][half][l * 4096 + wv * 512], 16, 0, 0);              \
  }
#define STG_B(buf, half, kt)                                                     \
  {                                                                              \
    _Pragma("unroll")                                                            \
    for (int l = 0; l < 2; ++l)                                                  \
      __builtin_amdgcn_global_load_lds(                                          \
          (const AS1 u32*)(Bt + (size_t)(colBase + (half) * 128 + l * 64 + wv * 8 + lr8) * 1024 + (kt) * 64 + schunk), \
          (AS3 u32*)&sB[buf][half][l * 4096 + wv * 512], 16, 0, 0);              \
  }
  // swizzled fragment reads (row&7 == l16&7 since frag row = m*16+l16)
#define RD_A(buf, m, ks) \
  u2b8(*(const u16x8*)&sA[buf][wr][(((m) * 16 + l16) << 6) + ((((ks) * 4 + lq) ^ (l16 & 7)) << 3)])
#define RD_B(buf, n, ks) \
  u2b8(*(const u16x8*)&sB[buf][wc >> 1][(((wc & 1) * 64 + (n) * 16 + l16) << 6) + ((((ks) * 4 + lq) ^ (l16 & 7)) << 3)])
#define BAR() asm volatile("s_barrier" ::: "memory")

  f32x4 acc[8][4] = {};

  // ---- prologue: 6 half-tiles, keep 2 newest (B(1)) in flight ----
  STG_A(0, 0, 0); STG_A(0, 1, 0);
  STG_B(0, 0, 0); STG_B(0, 1, 0);
  STG_B(1, 0, 1); STG_B(1, 1, 1);
  asm volatile("s_waitcnt vmcnt(4)" ::: "memory");
  BAR();

  bf16x8 a0[4][2], a1[4][2], b0[2][2], b1[2][2];
  const int NT = 16;
  for (int t = 0; t < NT; ++t) {
    const int buf = t & 1;
    // ---------------- phase 1: Q0 = m0-3 x n0-1 ----------------
    #pragma unroll
    for (int m = 0; m < 4; ++m) { a0[m][0] = RD_A(buf, m, 0); a0[m][1] = RD_A(buf, m, 1); }
    #pragma unroll
    for (int n = 0; n < 2; ++n) { b0[n][0] = RD_B(buf, n, 0); b0[n][1] = RD_B(buf, n, 1); }
    if (t + 1 < NT) STG_A(buf ^ 1, 0, t + 1);
    BAR();
    __builtin_amdgcn_s_setprio(1);
    #pragma unroll
    for (int m = 0; m < 4; ++m)
      #pragma unroll
      for (int n = 0; n < 2; ++n) {
        acc[m][n] = __builtin_amdgcn_mfma_f32_16x16x32_bf16(a0[m][0], b0[n][0], acc[m][n], 0, 0, 0);
        acc[m][n] = __builtin_amdgcn_mfma_f32_16x16x32_bf16(a0[m][1], b0[n][1], acc[m][n], 0, 0, 0);
      }
    __builtin_amdgcn_s_setprio(0);
    BAR();
    // ---------------- phase 2: Q1 = m0-3 x n2-3 ----------------
    #pragma unroll
    for (int n = 0; n < 2; ++n) { b1[n][0] = RD_B(buf, n + 2, 0); b1[n][1] = RD_B(buf, n + 2, 1); }
    if (t + 1 < NT) STG_A(buf ^ 1, 1, t + 1);
    BAR();
    __builtin_amdgcn_s_setprio(1);
    #pragma unroll
    for (int m = 0; m < 4; ++m)
      #pragma unroll
      for (int n = 0; n < 2; ++n) {
        acc[m][n + 2] = __builtin_amdgcn_mfma_f32_16x16x32_bf16(a0[m][0], b1[n][0], acc[m][n + 2], 0, 0, 0);
        acc[m][n + 2] = __builtin_amdgcn_mfma_f32_16x16x32_bf16(a0[m][1], b1[n][1], acc[m][n + 2], 0, 0, 0);
      }
    __builtin_amdgcn_s_setprio(0);
    BAR();
    // ---------------- phase 3: Q2 = m4-7 x n0-1 ----------------
    #pragma unroll
    for (int m = 0; m < 4; ++m) { a1[m][0] = RD_A(buf, m + 4, 0); a1[m][1] = RD_A(buf, m + 4, 1); }
    if (t + 2 < NT) STG_B(buf, 0, t + 2);
    BAR();
    __builtin_amdgcn_s_setprio(1);
    #pragma unroll
    for (int m = 0; m < 4; ++m)
      #pragma unroll
      for (int n = 0; n < 2; ++n) {
        acc[m + 4][n] = __builtin_amdgcn_mfma_f32_16x16x32_bf16(a1[m][0], b0[n][0], acc[m + 4][n], 0, 0, 0);
        acc[m + 4][n] = __builtin_amdgcn_mfma_f32_16x16x32_bf16(a1[m][1], b0[n][1], acc[m + 4][n], 0, 0, 0);
      }
    __builtin_amdgcn_s_setprio(0);
    BAR();
    // ---------------- phase 4: Q3 = m4-7 x n2-3 ----------------
    if (t + 2 < NT) {
      STG_B(buf, 1, t + 2);
      asm volatile("s_waitcnt vmcnt(4)" ::: "memory");   // keep ph3/ph4 B-stages
    } else {
      asm volatile("s_waitcnt vmcnt(0)" ::: "memory");   // drain tail (A(15))
    }
    BAR();
    __builtin_amdgcn_s_setprio(1);
    #pragma unroll
    for (int m = 0; m < 4; ++m)
      #pragma unroll
      for (int n = 0; n < 2; ++n) {
        acc[m + 4][n + 2] = __builtin_amdgcn_mfma_f32_16x16x32_bf16(a1[m][0], b1[n][0], acc[m + 4][n + 2], 0, 0, 0);
        acc[m + 4][n + 2] = __builtin_amdgcn_mfma_f32_16x16x32_bf16(a1[m][1], b1[n][1], acc[m + 4][n + 2], 0, 0, 0);
      }
    __builtin_amdgcn_s_setprio(0);
    BAR();
  }
#undef STG_A
#undef STG_B
#undef RD_A
#undef RD_B
#undef BAR

  // ---- RoPE epilogue + scatter (C/D: col=l16, row=lq*4+j; verified) ----
  const int which = colBase >> 10;                      // block-uniform
  const int head = ((colBase + wc * 64) >> 6) & 15;
  const float QSC = 0.125f * 1.44269504f;
  u16* const dst = (which == 0) ? qr : (which == 1) ? kr : vrp;
  #pragma unroll
  for (int m = 0; m < 8; ++m) {
    #pragma unroll
    for (int n = 0; n < 4; ++n) {
      const int d0 = n * 16 + l16;                      // d within head
      #pragma unroll
      for (int j = 0; j < 4; ++j) {
        int row = rowBase + wr * 128 + m * 16 + lq * 4 + j;
        int b = row >> 11, t = row & 2047;
        float v = acc[m][n][j];
        u16 outv;
        if (which == 2) {
          outv = f2b(v);
        } else {
          float p = __shfl_xor(v, 1);                   // RoPE partner (d0^1)
          float2 cs = csT[t * 32 + (d0 >> 1)];
          float r = (l16 & 1) ? fmaf(p, cs.y, v * cs.x)
                              : fmaf(-p, cs.y, v * cs.x);
          if (which == 0) r *= QSC;
          outv = f2b(r);
        }
        dst[((size_t)(b * 16 + head) * 2048 + t) * 64 + d0] = outv;
      }
    }
  }
}

// ------------------------- 128^2 GEMM (out-proj) ---------------------------
// C[M,N] = A[M,K] * Bt[N,K]^T, bf16 in, float out. 128x128 tile, BK=32,
// 4 waves, global_load_lds(16), 3-buffer distance-2 pipeline (R9).
__global__ __launch_bounds__(256) void gemm_bt_kernel(const u16* __restrict__ A,
                                                      const u16* __restrict__ Bt,
                                                      float* __restrict__ Cm,
                                                      int M, int N, int K) {
  __shared__ u16 sA[3][128 * 32];
  __shared__ u16 sB[3][128 * 32];
  const int tid = threadIdx.x;
  const int lane = tid & 63;
  const int wv = tid >> 6;
  const int wr = wv >> 1, wc = wv & 1;
  const int l16 = lane & 15, lq = lane >> 4;
  const int rowBase = blockIdx.y * 128;
  const int colBase = blockIdx.x * 128;

  f32x4 acc[4][4] = {};

  const int e0 = wv * 1024 + lane * 8;      // this lane's elem offset, chunk 0

#define GSTAGE(buf, kk)                                                          \
  {                                                                              \
    _Pragma("unroll")                                                            \
    for (int s = 0; s < 2; ++s) {                                                \
      int e = e0 + s * 512;                                                      \
      int r = e >> 5, ccc = e & 31;                                              \
      __builtin_amdgcn_global_load_lds(                                          \
          (const AS1 u32*)(A + (size_t)(rowBase + r) * K + (kk) + ccc),          \
          (AS3 u32*)&sA[buf][wv * 1024 + s * 512], 16, 0, 0);                    \
      __builtin_amdgcn_global_load_lds(                                          \
          (const AS1 u32*)(Bt + (size_t)(colBase + r) * K + (kk) + ccc),         \
          (AS3 u32*)&sB[buf][wv * 1024 + s * 512], 16, 0, 0);                    \
    }                                                                            \
  }

  const int NT = K >> 5;                 // K/32 tiles
  GSTAGE(0, 0);
  if (NT > 1) GSTAGE(1, 32);

  int cur = 0;
  for (int kt = 0; kt < NT; ++kt) {
    if (kt + 1 < NT) {
      asm volatile("s_waitcnt vmcnt(4)" ::: "memory");   // tile kt landed (own)
    } else {
      asm volatile("s_waitcnt vmcnt(0)" ::: "memory");   // final tile
    }
    __builtin_amdgcn_s_barrier();        // tile kt visible; k-1 reads done

    if (kt + 2 < NT) {
      int nb = cur + 2; if (nb >= 3) nb -= 3;
      GSTAGE(nb, (kt + 2) * 32);         // overlaps this iter's compute
    }

    bf16x8 af[4], bf[4];
    #pragma unroll
    for (int m = 0; m < 4; ++m)
      af[m] = u2b8(*(const u16x8*)&sA[cur][(wr * 64 + m * 16 + l16) * 32 + lq * 8]);
    #pragma unroll
    for (int n = 0; n < 4; ++n)
      bf[n] = u2b8(*(const u16x8*)&sB[cur][(wc * 64 + n * 16 + l16) * 32 + lq * 8]);
    __builtin_amdgcn_s_setprio(1);
    #pragma unroll
    for (int m = 0; m < 4; ++m)
      #pragma unroll
      for (int n = 0; n < 4; ++n)
        acc[m][n] = __builtin_amdgcn_mfma_f32_16x16x32_bf16(af[m], bf[n], acc[m][n], 0, 0, 0);
    __builtin_amdgcn_s_setprio(0);

    cur = (cur + 1 == 3) ? 0 : cur + 1;
  }
#undef GSTAGE

  // C/D layout (verified m89): col = lane&15, row = (lane>>4)*4 + reg
  #pragma unroll
  for (int m = 0; m < 4; ++m)
    #pragma unroll
    for (int n = 0; n < 4; ++n) {
      int row = rowBase + wr * 64 + m * 16 + lq * 4;
      int col = colBase + wc * 64 + n * 16 + l16;
      #pragma unroll
      for (int j = 0; j < 4; ++j)
        Cm[(size_t)(row + j) * N + col] = acc[m][n][j];
    }
}

// ------------------------- MFMA flash attention ----------------------------
// R9 structure: 16 q-rows/wave, swapped QK^T, in-register P via k-slot
// permutation (V rows staged bit-permuted vrow=[b5 b2 b4 b3 b1 b0] so PV
// A-operand = own exp2'd registers), double-buffered K/V, T14 prefetch,
// ONE barrier per tile, launch_bounds(256,4). K staged by global_load_lds
// into linear [64][64] with chunk swizzle (slot (r,c) holds chunk c^(r&7)).
__global__ __launch_bounds__(256, 4) void attn_mfma_kernel(const u16* __restrict__ qr,
                                                           const u16* __restrict__ kr,
                                                           const u16* __restrict__ vr,
                                                           u16* __restrict__ ao) {
  constexpr int LDVT = 72;
  __shared__ u16 sK[2][64 * 64];                 // linear, chunk-swizzled
  __shared__ u16 sVt[2][64 * LDVT];              // sVt[buf][d][k-slot]

  const int tid = threadIdx.x;
  const int lane = tid & 63;
  const int w = tid >> 6;
  const int l16 = lane & 15, lq = lane >> 4;
  const int bh = blockIdx.x;
  const int qt = (int)gridDim.y - 1 - (int)blockIdx.y;   // long blocks first
  const int qbase = qt * 64;
  const size_t hb = (size_t)bh * (T_ * D_);

  // Q frags (pre-scaled bf16): rows qbase + w*16 + l16
  bf16x8 qv[2];
  #pragma unroll
  for (int dc = 0; dc < 2; ++dc) {
    int row = qbase + w * 16 + l16;
    qv[dc] = u2b8(*(const u16x8*)(qr + hb + (size_t)row * 64 + dc * 32 + lq * 8));
  }

  f32x4 o[4] = {};              // o[dt]: O[q=lq*4+j][d=dt*16+l16]
  float mrow = -1e30f;          // running max (log2 domain), row q=l16
  float lrow = 0.0f;            // per-lane partial denom, row q=l16

  // K DMA maps: wave w covers rows w*16 + s*8 + (lane>>3), chunk lane&7.
  const int krow0 = w * 16 + (lane >> 3);
  const int ksrc = ((lane & 7) ^ (lane >> 3)) * 8;   // elem offset in row
  // V staging maps (reg path)
  const int vkp = tid & 31;           // V slot-pair 0..31 (slots 2vkp, 2vkp+1)
  const int vdb = tid >> 5;           // V d-block 0..7
  const int vtr = ((vkp >> 4) & 1) * 32 + ((vkp >> 1) & 1) * 16 +
                  ((vkp >> 3) & 1) * 8 + ((vkp >> 2) & 1) * 4 + (vkp & 1) * 2;

  u16x8 rv0, rv1;
#define STAGEK(buf, k0s)                                                       \
  {                                                                            \
    _Pragma("unroll")                                                          \
    for (int s = 0; s < 2; ++s)                                                \
      __builtin_amdgcn_global_load_lds(                                        \
          (const AS1 u32*)(kr + hb + (size_t)((k0s) + krow0 + s * 8) * 64 + ksrc), \
          (AS3 u32*)&sK[buf][(w * 16 + s * 8) * 64], 16, 0, 0);                \
  }
#define LOADV(k0s)                                                             \
  {                                                                            \
    rv0 = *(const u16x8*)(vr + hb + (size_t)((k0s) + vtr) * 64 + vdb * 8);     \
    rv1 = *(const u16x8*)(vr + hb + (size_t)((k0s) + vtr + 1) * 64 + vdb * 8); \
  }
#define WRITEV(buf)                                                            \
  {                                                                            \
    _Pragma("unroll")                                                          \
    for (int u = 0; u < 8; ++u) {                                              \
      u16x2 pk; pk[0] = rv0[u]; pk[1] = rv1[u];                                \
      *(u16x2*)&sVt[buf][(vdb * 8 + u) * LDVT + 2 * vkp] = pk;                 \
    }                                                                          \
  }

  STAGEK(0, 0);
  LOADV(0);
  WRITEV(0);
  __syncthreads();               // drains vmcnt (K DMA) + LDS writes

  const int nt = qt + 1;
  int cur = 0;
  for (int it = 0; it < nt; ++it) {
    const int k0 = it * 64;
    const bool more = (it + 1 < nt);
    if (more) {
      STAGEK(cur ^ 1, k0 + 64);        // async DMA into other buffer
      LOADV(k0 + 64);                  // V prefetch into regs (T14)
    }

    // ---- QK^T (swapped): accs[kt][j] = S[q=l16][slot k0+kt*16+lq*4+j]
    f32x4 accs[4] = {};
    __builtin_amdgcn_s_setprio(1);
    #pragma unroll
    for (int kt = 0; kt < 4; ++kt) {
      int chy = ((lq) ^ (l16 & 7)) * 8;        // dc=0 chunk
      int chz = ((4 + lq) ^ (l16 & 7)) * 8;    // dc=1 chunk
      bf16x8 kf0 = u2b8(*(const u16x8*)&sK[cur][(kt * 16 + l16) * 64 + chy]);
      bf16x8 kf1 = u2b8(*(const u16x8*)&sK[cur][(kt * 16 + l16) * 64 + chz]);
      accs[kt] = __builtin_amdgcn_mfma_f32_16x16x32_bf16(kf0, qv[0], accs[kt], 0, 0, 0);
      accs[kt] = __builtin_amdgcn_mfma_f32_16x16x32_bf16(kf1, qv[1], accs[kt], 0, 0, 0);
    }
    __builtin_amdgcn_s_setprio(0);

    const int qrow = qbase + w * 16 + l16;
    if (k0 + 63 > qbase + w * 16) {      // wave-uniform: diagonal tile only
      #pragma unroll
      for (int kt = 0; kt < 4; ++kt)
        #pragma unroll
        for (int j = 0; j < 4; ++j)
          if (k0 + kt * 16 + lq * 4 + j > qrow) accs[kt][j] = -1e30f;
    }
    // row max for q=l16: depth-4 tree + 2 shfl (k spread across lq groups)
    float m0 = fmaxf(fmaxf(accs[0][0], accs[0][1]), fmaxf(accs[0][2], accs[0][3]));
    float m1 = fmaxf(fmaxf(accs[1][0], accs[1][1]), fmaxf(accs[1][2], accs[1][3]));
    float m2 = fmaxf(fmaxf(accs[2][0], accs[2][1]), fmaxf(accs[2][2], accs[2][3]));
    float m3 = fmaxf(fmaxf(accs[3][0], accs[3][1]), fmaxf(accs[3][2], accs[3][3]));
    float mx = fmaxf(fmaxf(m0, m1), fmaxf(m2, m3));
    mx = fmaxf(mx, __shfl_xor(mx, 16));
    mx = fmaxf(mx, __shfl_xor(mx, 32));

    if (!__all(mx <= mrow)) {            // defer-max: exact skip when no new max
      float mnew = fmaxf(mrow, mx);
      float corr = __builtin_amdgcn_exp2f(mrow - mnew);   // row q=l16
      lrow *= corr;
      mrow = mnew;
      // broadcast corr into D-row space (q=lq*4+j) before scaling O
      f32x4 corrv;
      #pragma unroll
      for (int j = 0; j < 4; ++j) corrv[j] = __shfl(corr, lq * 4 + j);
      #pragma unroll
      for (int dt = 0; dt < 4; ++dt) o[dt] *= corrv;
    }
    const float mu = mrow;
    // exp2 + pack: pb[kc][u] : u<4 <- slot kt=2kc, u>=4 <- kt=2kc+1
    bf16x8 pb[2];
    float lsum = 0.0f;
    #pragma unroll
    for (int kt = 0; kt < 4; ++kt) {
      #pragma unroll
      for (int j = 0; j < 4; ++j) {
        float p = __builtin_amdgcn_exp2f(accs[kt][j] - mu);
        lsum += p;
        pb[kt >> 1][(kt & 1) * 4 + j] = (__bf16)p;   // -> v_cvt_pk_bf16_f32
      }
    }
    lrow += lsum;

    // ---- PV: A-operand = own registers (slot perm); B from sVt ----
    __builtin_amdgcn_s_setprio(1);
    #pragma unroll
    for (int kc = 0; kc < 2; ++kc) {
      #pragma unroll
      for (int dt = 0; dt < 4; ++dt) {
        bf16x8 vt = u2b8(*(const u16x8*)&sVt[cur][(dt * 16 + l16) * LDVT + kc * 32 + lq * 8]);
        o[dt] = __builtin_amdgcn_mfma_f32_16x16x32_bf16(pb[kc], vt, o[dt], 0, 0, 0);
      }
    }
    __builtin_amdgcn_s_setprio(0);

    if (more) WRITEV(cur ^ 1);           // V^T into other buffer (reads were cur)
    __syncthreads();                     // one barrier/tile; drains K DMA too
    cur ^= 1;
  }

  // finalize: full row denom in l16-space, broadcast 1/l into D-row space.
  const int b = bh >> 4, h = bh & 15;
  float l = lrow;
  l += __shfl_xor(l, 16);
  l += __shfl_xor(l, 32);
  float linv = 1.0f / l;
  #pragma unroll
  for (int j = 0; j < 4; ++j) {
    float lj = __shfl(linv, lq * 4 + j);   // lane r (r<16) holds row r's denom
    int row = qbase + w * 16 + lq * 4 + j;
    u16* orow = ao + ((size_t)(b * T_ + row)) * C_ + h * 64;
    #pragma unroll
    for (int dt = 0; dt < 4; ++dt)
      orow[dt * 16 + l16] = f2b(o[dt][j] * lj);
  }
}

// ------------------------------- launcher ----------------------------------
// ws layout (bytes):                              size
//   xb     @ 0           bf16 x           8,388,608
//   wqkvT  @ 8388608     bf16 w_qkv^T     6,291,456
//   woutT  @ 14680064    bf16 w_out^T     2,097,152
//   qr     @ 41943040    bf16 [B,H,T,D]   8,388,608
//   kr     @ 50331648                     8,388,608
//   vr     @ 58720256                     8,388,608
//   ao     @ 67108864    bf16 attn out    8,388,608
//   csT    @ 75497472    f32x2 rope tbl     524,288
extern "C" void kernel_launch(void* const* d_in, const int* in_sizes, int n_in,
                              void* d_out, int out_size, void* d_ws, size_t ws_size,
                              hipStream_t stream) {
  const float* x     = (const float*)d_in[0];
  const float* w_qkv = (const float*)d_in[1];
  const float* w_out = (const float*)d_in[2];
  float* out = (float*)d_out;
  char* ws = (char*)d_ws;

  u16* xb     = (u16*)(ws + 0);
  u16* wqkvT  = (u16*)(ws + 8388608);
  u16* woutT  = (u16*)(ws + 14680064);
  u16* qr     = (u16*)(ws + 41943040);
  u16* kr     = (u16*)(ws + 50331648);
  u16* vr     = (u16*)(ws + 58720256);
  u16* ao     = (u16*)(ws + 67108864);
  float2* csT = (float2*)(ws + 75497472);

  rope_table_kernel<<<256, 256, 0, stream>>>(csT);
  cast_x_kernel<<<4096, 256, 0, stream>>>(x, xb);
  transpose_cast_kernel<<<dim3(96, 32), 256, 0, stream>>>(w_qkv, wqkvT, C_, F_);
  transpose_cast_kernel<<<dim3(32, 32), 256, 0, stream>>>(w_out, woutT, C_, C_);
  gemm256_qkv_kernel<<<dim3(12, 16), 512, 0, stream>>>(xb, wqkvT, qr, kr, vr, (const float2*)csT);
  attn_mfma_kernel<<<dim3(B_ * H_, T_ / 64), 256, 0, stream>>>(qr, kr, vr, ao);
  gemm_bt_kernel<<<dim3(C_ / 128, M_ / 128), 256, 0, stream>>>(ao, woutT, out, M_, C_, C_);
}

// Round 13
// 146.413 us; speedup vs baseline: 1.0194x; 1.0194x over previous
//
#include <hip/hip_runtime.h>
#include <stdint.h>

// ---------------------------------------------------------------------------
// MultiHeadSelfAttention: x(2,2048,1024) fp32, w_qkv(1024,3072), w_out(1024,1024)
// R12: (a) qkv GEMM reverted to the proven 128^2 distance-2 kernel (R11's
// 8-phase port = 406 TF at 1 block/CU: conflicts 0 but barrier-drain bound).
// (b) attn: 32 q-rows/wave retry (R5) with the spill causes removed — K is
// DMA-staged (no rk regs) and launch_bounds(256,2) -> VGPR cap 128 (empirical
// map: cap = 512/(2N); R5's (256,4)=64 cap caused the spill). Halves K/V
// ds_reads, V staging, and loop overhead per q-row.
// ---------------------------------------------------------------------------

#define B_ 2
#define T_ 2048
#define C_ 1024
#define H_ 16
#define D_ 64
#define F_ 3072
#define M_ 4096

typedef unsigned short u16;
typedef unsigned int u32;
typedef u16 u16x2 __attribute__((ext_vector_type(2)));
typedef u16 u16x4 __attribute__((ext_vector_type(4)));
typedef u16 u16x8 __attribute__((ext_vector_type(8)));
typedef __bf16 bf16x8 __attribute__((ext_vector_type(8)));
typedef float f32x4 __attribute__((ext_vector_type(4)));

#define AS1 __attribute__((address_space(1)))
#define AS3 __attribute__((address_space(3)))

__device__ __forceinline__ float b2f(u16 u) {
  union { unsigned int i; float f; } v; v.i = ((unsigned int)u) << 16; return v.f;
}
__device__ __forceinline__ u16 f2b(float f) {  // RNE, finite inputs
  unsigned int u = __float_as_uint(f);
  u += 0x7fffu + ((u >> 16) & 1u);
  return (u16)(u >> 16);
}
__device__ __forceinline__ bf16x8 u2b8(u16x8 v) {
  union { u16x8 u; bf16x8 b; } x; x.u = v; return x.b;
}

// --------------------------- small prep kernels ----------------------------

// interleaved {cos,sin} table: csT[t*32+i] = {cos(t*f_i), sin(t*f_i)}
__global__ __launch_bounds__(256) void rope_table_kernel(float2* csT) {
  int idx = blockIdx.x * 256 + threadIdx.x;    // T_*32 = 65536 threads
  int t = idx >> 5, i = idx & 31;
  float inv_freq = powf(10000.0f, -(float)(2 * i) / 64.0f);
  float ang = (float)t * inv_freq;
  csT[idx] = make_float2(cosf(ang), sinf(ang));
}

__global__ __launch_bounds__(256) void cast_x_kernel(const float* __restrict__ x,
                                                     u16* __restrict__ xb) {
  int i = blockIdx.x * 256 + threadIdx.x;      // M_*C_/4 threads
  float4 v = ((const float4*)x)[i];
  u16x4 r;
  r[0] = f2b(v.x); r[1] = f2b(v.y); r[2] = f2b(v.z); r[3] = f2b(v.w);
  ((u16x4*)xb)[i] = r;
}

// out[c][r] = bf16(in[r][c]);  R rows, Ccol cols in input. 32x32 tiles.
__global__ __launch_bounds__(256) void transpose_cast_kernel(const float* __restrict__ in,
                                                             u16* __restrict__ out,
                                                             int R, int Ccol) {
  __shared__ float tile[32][33];
  int c0 = blockIdx.x * 32, r0 = blockIdx.y * 32;
  int tx = threadIdx.x & 31, ty = threadIdx.x >> 5;   // ty = 0..7
  #pragma unroll
  for (int i = 0; i < 32; i += 8)
    tile[ty + i][tx] = in[(size_t)(r0 + ty + i) * Ccol + c0 + tx];
  __syncthreads();
  #pragma unroll
  for (int i = 0; i < 32; i += 8)
    out[(size_t)(c0 + ty + i) * R + r0 + tx] = f2b(tile[tx][ty + i]);
}

// ------------------------------- MFMA GEMM ---------------------------------
// C[M,N] = A[M,K] * Bt[N,K]^T, bf16 in. 128x128 tile, BK=32, 4 waves, 4x4
// 16x16x32 frags, global_load_lds(16) staging, 3-buffer distance-2 pipeline.
// MODE 0: float out to Cm.
// MODE 2: QKV epilogue — RoPE(q,k via lane-pair shfl + csT) + scatter to
//         qr/kr/vr [B,H,T,D]; q pre-scaled by 0.125*log2(e).
template <int MODE>
__global__ __launch_bounds__(256) void gemm_bt_kernel(const u16* __restrict__ A,
                                                      const u16* __restrict__ Bt,
                                                      float* __restrict__ Cm,
                                                      u16* __restrict__ qr,
                                                      u16* __restrict__ kr,
                                                      u16* __restrict__ vrp,
                                                      const float2* __restrict__ csT,
                                                      int M, int N, int K) {
  __shared__ u16 sA[3][128 * 32];
  __shared__ u16 sB[3][128 * 32];
  const int tid = threadIdx.x;
  const int lane = tid & 63;
  const int wv = tid >> 6;
  const int wr = wv >> 1, wc = wv & 1;
  const int l16 = lane & 15, lq = lane >> 4;
  const int rowBase = blockIdx.y * 128;
  const int colBase = blockIdx.x * 128;

  f32x4 acc[4][4] = {};

  const int e0 = wv * 1024 + lane * 8;      // this lane's elem offset, chunk 0

#define GSTAGE(buf, kk)                                                          \
  {                                                                              \
    _Pragma("unroll")                                                            \
    for (int s = 0; s < 2; ++s) {                                                \
      int e = e0 + s * 512;                                                      \
      int r = e >> 5, ccc = e & 31;                                              \
      __builtin_amdgcn_global_load_lds(                                          \
          (const AS1 u32*)(A + (size_t)(rowBase + r) * K + (kk) + ccc),          \
          (AS3 u32*)&sA[buf][wv * 1024 + s * 512], 16, 0, 0);                    \
      __builtin_amdgcn_global_load_lds(                                          \
          (const AS1 u32*)(Bt + (size_t)(colBase + r) * K + (kk) + ccc),         \
          (AS3 u32*)&sB[buf][wv * 1024 + s * 512], 16, 0, 0);                    \
    }                                                                            \
  }

  const int NT = K >> 5;                 // K/32 tiles
  GSTAGE(0, 0);
  if (NT > 1) GSTAGE(1, 32);

  int cur = 0;
  for (int kt = 0; kt < NT; ++kt) {
    if (kt + 1 < NT) {
      asm volatile("s_waitcnt vmcnt(4)" ::: "memory");   // tile kt landed (own)
    } else {
      asm volatile("s_waitcnt vmcnt(0)" ::: "memory");   // final tile
    }
    __builtin_amdgcn_s_barrier();        // tile kt visible; k-1 reads done

    if (kt + 2 < NT) {
      int nb = cur + 2; if (nb >= 3) nb -= 3;
      GSTAGE(nb, (kt + 2) * 32);         // overlaps this iter's compute
    }

    bf16x8 af[4], bf[4];
    #pragma unroll
    for (int m = 0; m < 4; ++m)
      af[m] = u2b8(*(const u16x8*)&sA[cur][(wr * 64 + m * 16 + l16) * 32 + lq * 8]);
    #pragma unroll
    for (int n = 0; n < 4; ++n)
      bf[n] = u2b8(*(const u16x8*)&sB[cur][(wc * 64 + n * 16 + l16) * 32 + lq * 8]);
    __builtin_amdgcn_s_setprio(1);
    #pragma unroll
    for (int m = 0; m < 4; ++m)
      #pragma unroll
      for (int n = 0; n < 4; ++n)
        acc[m][n] = __builtin_amdgcn_mfma_f32_16x16x32_bf16(af[m], bf[n], acc[m][n], 0, 0, 0);
    __builtin_amdgcn_s_setprio(0);

    cur = (cur + 1 == 3) ? 0 : cur + 1;
  }
#undef GSTAGE

  // C/D layout (verified m89): col = lane&15, row = (lane>>4)*4 + reg
  if constexpr (MODE == 0) {
    #pragma unroll
    for (int m = 0; m < 4; ++m)
      #pragma unroll
      for (int n = 0; n < 4; ++n) {
        int row = rowBase + wr * 64 + m * 16 + lq * 4;
        int col = colBase + wc * 64 + n * 16 + l16;
        #pragma unroll
        for (int j = 0; j < 4; ++j)
          Cm[(size_t)(row + j) * N + col] = acc[m][n][j];
      }
  } else {
    // which: 0=q 1=k 2=v (block-uniform); head: uniform per (wave,n-range)
    const int which = colBase >> 10;
    const int head = ((colBase + wc * 64) >> 6) & 15;
    const float QSC = 0.125f * 1.44269504f;
    u16* const dst = (which == 0) ? qr : (which == 1) ? kr : vrp;
    #pragma unroll
    for (int m = 0; m < 4; ++m) {
      #pragma unroll
      for (int n = 0; n < 4; ++n) {
        const int d0 = n * 16 + l16;           // d within head (0..63)
        #pragma unroll
        for (int j = 0; j < 4; ++j) {
          int row = rowBase + wr * 64 + m * 16 + lq * 4 + j;
          int b = row >> 11, t = row & 2047;
          float v = acc[m][n][j];
          u16 outv;
          if (which == 2) {
            outv = f2b(v);
          } else {
            float p = __shfl_xor(v, 1);        // RoPE partner (d0^1)
            float2 cs = csT[t * 32 + (d0 >> 1)];
            float r = (l16 & 1) ? fmaf(p, cs.y, v * cs.x)    // odd:  xe*s + xo*c
                                : fmaf(-p, cs.y, v * cs.x);  // even: xe*c - xo*s
            if (which == 0) r *= QSC;
            outv = f2b(r);
          }
          dst[((size_t)(b * 16 + head) * 2048 + t) * 64 + d0] = outv;
        }
      }
    }
  }
}

// ------------------------- MFMA flash attention ----------------------------
// 32 q-rows/wave (2 qf frags), 128 q/block, grid (32,16). Swapped QK^T;
// softmax state in q=l16 space, O accumulator in q=lq*4+j space; cross-space
// via __shfl(.., lq*4+j). In-register P via k-slot permutation (V rows staged
// bit-permuted vrow=[b5 b2 b4 b3 b1 b0]). K staged by global_load_lds DMA into
// linear [64][64] with chunk swizzle (slot (r,c) holds chunk c^(r&7)).
// K-frags and V-frags read ONCE per tile, shared by both qf. Double buffer,
// T14 prefetch, ONE barrier/tile. launch_bounds(256,2): VGPR cap 128
// (empirical: cap = 512/(2N)); est. live ~124 — WRITE_SIZE is the spill check.
__global__ __launch_bounds__(256, 2) void attn_mfma_kernel(const u16* __restrict__ qr,
                                                           const u16* __restrict__ kr,
                                                           const u16* __restrict__ vr,
                                                           u16* __restrict__ ao) {
  constexpr int LDVT = 72;
  __shared__ u16 sK[2][64 * 64];                 // linear, chunk-swizzled
  __shared__ u16 sVt[2][64 * LDVT];              // sVt[buf][d][k-slot]

  const int tid = threadIdx.x;
  const int lane = tid & 63;
  const int w = tid >> 6;
  const int l16 = lane & 15, lq = lane >> 4;
  const int bh = blockIdx.x;
  const int qt = (int)gridDim.y - 1 - (int)blockIdx.y;   // long blocks first
  const int qbase = qt * 128;                            // 128 q-rows/block
  const size_t hb = (size_t)bh * (T_ * D_);

  // Q frags (pre-scaled bf16): rows qbase + w*32 + qf*16 + l16
  bf16x8 qv[2][2];
  #pragma unroll
  for (int qf = 0; qf < 2; ++qf)
    #pragma unroll
    for (int dc = 0; dc < 2; ++dc) {
      int row = qbase + w * 32 + qf * 16 + l16;
      qv[qf][dc] = u2b8(*(const u16x8*)(qr + hb + (size_t)row * 64 + dc * 32 + lq * 8));
    }

  f32x4 o[2][4] = {};                 // o[qf][dt]: O[q=lq*4+j][d=dt*16+l16]
  float mrow[2] = {-1e30f, -1e30f};   // running max (log2 domain), row q=l16
  float lrow[2] = {0.0f, 0.0f};       // per-lane partial denom, row q=l16

  // K DMA maps: wave w covers rows w*16 + s*8 + (lane>>3), chunk lane&7.
  const int krow0 = w * 16 + (lane >> 3);
  const int ksrc = ((lane & 7) ^ (lane >> 3)) * 8;   // elem offset in row
  // V staging maps (reg path)
  const int vkp = tid & 31;           // V slot-pair 0..31 (slots 2vkp, 2vkp+1)
  const int vdb = tid >> 5;           // V d-block 0..7
  const int vtr = ((vkp >> 4) & 1) * 32 + ((vkp >> 1) & 1) * 16 +
                  ((vkp >> 3) & 1) * 8 + ((vkp >> 2) & 1) * 4 + (vkp & 1) * 2;

  u16x8 rv0, rv1;
#define STAGEK(buf, k0s)                                                       \
  {                                                                            \
    _Pragma("unroll")                                                          \
    for (int s = 0; s < 2; ++s)                                                \
      __builtin_amdgcn_global_load_lds(                                        \
          (const AS1 u32*)(kr + hb + (size_t)((k0s) + krow0 + s * 8) * 64 + ksrc), \
          (AS3 u32*)&sK[buf][(w * 16 + s * 8) * 64], 16, 0, 0);                \
  }
#define LOADV(k0s)                                                             \
  {                                                                            \
    rv0 = *(const u16x8*)(vr + hb + (size_t)((k0s) + vtr) * 64 + vdb * 8);     \
    rv1 = *(const u16x8*)(vr + hb + (size_t)((k0s) + vtr + 1) * 64 + vdb * 8); \
  }
#define WRITEV(buf)                                                            \
  {                                                                            \
    _Pragma("unroll")                                                          \
    for (int u = 0; u < 8; ++u) {                                              \
      u16x2 pk; pk[0] = rv0[u]; pk[1] = rv1[u];                                \
      *(u16x2*)&sVt[buf][(vdb * 8 + u) * LDVT + 2 * vkp] = pk;                 \
    }                                                                          \
  }

  STAGEK(0, 0);
  LOADV(0);
  WRITEV(0);
  __syncthreads();               // drains vmcnt (K DMA) + LDS writes

  const int qmaxw = qbase + w * 32 + 31;   // max q-row this wave owns
  const int nt = qt * 2 + 2;
  int cur = 0;
  for (int it = 0; it < nt; ++it) {
    const int k0 = it * 64;
    const bool more = (it + 1 < nt);
    if (more) {
      STAGEK(cur ^ 1, k0 + 64);        // async DMA into other buffer
      LOADV(k0 + 64);                  // V prefetch into regs (T14)
    }

    if (k0 <= qmaxw) {                 // else fully masked for this wave
      // ---- QK^T (swapped): accs[qf][kt][j] = S[q=l16][slot k0+kt*16+lq*4+j]
      f32x4 accs[2][4] = {};
      __builtin_amdgcn_s_setprio(1);
      #pragma unroll
      for (int kt = 0; kt < 4; ++kt) {
        int chy = ((lq) ^ (l16 & 7)) * 8;        // dc=0 chunk
        int chz = ((4 + lq) ^ (l16 & 7)) * 8;    // dc=1 chunk
        bf16x8 kf0 = u2b8(*(const u16x8*)&sK[cur][(kt * 16 + l16) * 64 + chy]);
        bf16x8 kf1 = u2b8(*(const u16x8*)&sK[cur][(kt * 16 + l16) * 64 + chz]);
        accs[0][kt] = __builtin_amdgcn_mfma_f32_16x16x32_bf16(kf0, qv[0][0], accs[0][kt], 0, 0, 0);
        accs[0][kt] = __builtin_amdgcn_mfma_f32_16x16x32_bf16(kf1, qv[0][1], accs[0][kt], 0, 0, 0);
        accs[1][kt] = __builtin_amdgcn_mfma_f32_16x16x32_bf16(kf0, qv[1][0], accs[1][kt], 0, 0, 0);
        accs[1][kt] = __builtin_amdgcn_mfma_f32_16x16x32_bf16(kf1, qv[1][1], accs[1][kt], 0, 0, 0);
      }
      __builtin_amdgcn_s_setprio(0);

      bf16x8 pb[2][2];                 // pb[qf][kc]: PV A-operand (own regs)
      #pragma unroll
      for (int qf = 0; qf < 2; ++qf) {
        const int qrow = qbase + w * 32 + qf * 16 + l16;
        if (k0 + 63 > qbase + w * 32 + qf * 16) {   // wave-uniform per qf
          #pragma unroll
          for (int kt = 0; kt < 4; ++kt)
            #pragma unroll
            for (int j = 0; j < 4; ++j)
              if (k0 + kt * 16 + lq * 4 + j > qrow) accs[qf][kt][j] = -1e30f;
        }
        // row max for q=l16: depth-4 tree + 2 shfl (k spread across lq groups)
        float m0 = fmaxf(fmaxf(accs[qf][0][0], accs[qf][0][1]), fmaxf(accs[qf][0][2], accs[qf][0][3]));
        float m1 = fmaxf(fmaxf(accs[qf][1][0], accs[qf][1][1]), fmaxf(accs[qf][1][2], accs[qf][1][3]));
        float m2 = fmaxf(fmaxf(accs[qf][2][0], accs[qf][2][1]), fmaxf(accs[qf][2][2], accs[qf][2][3]));
        float m3 = fmaxf(fmaxf(accs[qf][3][0], accs[qf][3][1]), fmaxf(accs[qf][3][2], accs[qf][3][3]));
        float mx = fmaxf(fmaxf(m0, m1), fmaxf(m2, m3));
        mx = fmaxf(mx, __shfl_xor(mx, 16));
        mx = fmaxf(mx, __shfl_xor(mx, 32));

        if (!__all(mx <= mrow[qf])) {  // defer-max: exact skip when no new max
          float mnew = fmaxf(mrow[qf], mx);
          float corr = __builtin_amdgcn_exp2f(mrow[qf] - mnew);   // row q=l16
          lrow[qf] *= corr;
          mrow[qf] = mnew;
          // broadcast corr into D-row space (q=lq*4+j) before scaling O
          f32x4 corrv;
          #pragma unroll
          for (int j = 0; j < 4; ++j) corrv[j] = __shfl(corr, lq * 4 + j);
          #pragma unroll
          for (int dt = 0; dt < 4; ++dt) o[qf][dt] *= corrv;
        }
        const float mu = mrow[qf];
        float lsum = 0.0f;
        #pragma unroll
        for (int kt = 0; kt < 4; ++kt) {
          #pragma unroll
          for (int j = 0; j < 4; ++j) {
            float p = __builtin_amdgcn_exp2f(accs[qf][kt][j] - mu);
            lsum += p;
            pb[qf][kt >> 1][(kt & 1) * 4 + j] = (__bf16)p;   // v_cvt_pk_bf16_f32
          }
        }
        lrow[qf] += lsum;
      }

      // ---- PV: A = own registers (slot perm); B from sVt, shared across qf
      __builtin_amdgcn_s_setprio(1);
      #pragma unroll
      for (int kc = 0; kc < 2; ++kc) {
        #pragma unroll
        for (int dt = 0; dt < 4; ++dt) {
          bf16x8 vt = u2b8(*(const u16x8*)&sVt[cur][(dt * 16 + l16) * LDVT + kc * 32 + lq * 8]);
          o[0][dt] = __builtin_amdgcn_mfma_f32_16x16x32_bf16(pb[0][kc], vt, o[0][dt], 0, 0, 0);
          o[1][dt] = __builtin_amdgcn_mfma_f32_16x16x32_bf16(pb[1][kc], vt, o[1][dt], 0, 0, 0);
        }
      }
      __builtin_amdgcn_s_setprio(0);
    }

    if (more) WRITEV(cur ^ 1);           // V^T into other buffer (reads were cur)
    __syncthreads();                     // one barrier/tile; drains K DMA too
    cur ^= 1;
  }

  // finalize: full row denom in l16-space, broadcast 1/l into D-row space.
  const int b = bh >> 4, h = bh & 15;
  #pragma unroll
  for (int qf = 0; qf < 2; ++qf) {
    float l = lrow[qf];
    l += __shfl_xor(l, 16);
    l += __shfl_xor(l, 32);
    float linv = 1.0f / l;
    #pragma unroll
    for (int j = 0; j < 4; ++j) {
      float lj = __shfl(linv, lq * 4 + j);   // lane r (r<16) holds row r's denom
      int row = qbase + w * 32 + qf * 16 + lq * 4 + j;
      u16* orow = ao + ((size_t)(b * T_ + row)) * C_ + h * 64;
      #pragma unroll
      for (int dt = 0; dt < 4; ++dt)
        orow[dt * 16 + l16] = f2b(o[qf][dt][j] * lj);
    }
  }
}

// ------------------------------- launcher ----------------------------------
// ws layout (bytes):                              size
//   xb     @ 0           bf16 x           8,388,608
//   wqkvT  @ 8388608     bf16 w_qkv^T     6,291,456
//   woutT  @ 14680064    bf16 w_out^T     2,097,152
//   qr     @ 41943040    bf16 [B,H,T,D]   8,388,608
//   kr     @ 50331648                     8,388,608
//   vr     @ 58720256                     8,388,608
//   ao     @ 67108864    bf16 attn out    8,388,608
//   csT    @ 75497472    f32x2 rope tbl     524,288
extern "C" void kernel_launch(void* const* d_in, const int* in_sizes, int n_in,
                              void* d_out, int out_size, void* d_ws, size_t ws_size,
                              hipStream_t stream) {
  const float* x     = (const float*)d_in[0];
  const float* w_qkv = (const float*)d_in[1];
  const float* w_out = (const float*)d_in[2];
  float* out = (float*)d_out;
  char* ws = (char*)d_ws;

  u16* xb     = (u16*)(ws + 0);
  u16* wqkvT  = (u16*)(ws + 8388608);
  u16* woutT  = (u16*)(ws + 14680064);
  u16* qr     = (u16*)(ws + 41943040);
  u16* kr     = (u16*)(ws + 50331648);
  u16* vr     = (u16*)(ws + 58720256);
  u16* ao     = (u16*)(ws + 67108864);
  float2* csT = (float2*)(ws + 75497472);

  rope_table_kernel<<<256, 256, 0, stream>>>(csT);
  cast_x_kernel<<<4096, 256, 0, stream>>>(x, xb);
  transpose_cast_kernel<<<dim3(96, 32), 256, 0, stream>>>(w_qkv, wqkvT, C_, F_);
  transpose_cast_kernel<<<dim3(32, 32), 256, 0, stream>>>(w_out, woutT, C_, C_);
  gemm_bt_kernel<2><<<dim3(F_ / 128, M_ / 128), 256, 0, stream>>>(
      xb, wqkvT, nullptr, qr, kr, vr, (const float2*)csT, M_, F_, C_);
  attn_mfma_kernel<<<dim3(B_ * H_, T_ / 128), 256, 0, stream>>>(qr, kr, vr, ao);
  gemm_bt_kernel<0><<<dim3(C_ / 128, M_ / 128), 256, 0, stream>>>(
      ao, woutT, out, nullptr, nullptr, nullptr, nullptr, M_, C_, C_);
}

// Round 14
// 138.942 us; speedup vs baseline: 1.0742x; 1.0538x over previous
//
#include <hip/hip_runtime.h>
#include <stdint.h>

// ---------------------------------------------------------------------------
// MultiHeadSelfAttention: x(2,2048,1024) fp32, w_qkv(1024,3072), w_out(1024,1024)
// R13: (a) attn reverted to 16 q-rows/wave (R12's 32q/wave: no spill but grid
// 512 -> occ 11.5% -> slower; latency-bound regime needs blocks). (b) causal
// work-pairing: block p processes q-tiles {31-p, p} = constant 33 tiles ->
// uniform makespan, zero drain tail (grid 32x16, 2 blocks/CU). (c) T1
// bijective XCD swizzle on both GEMMs (768/256 blocks, %8==0).
// ---------------------------------------------------------------------------

#define B_ 2
#define T_ 2048
#define C_ 1024
#define H_ 16
#define D_ 64
#define F_ 3072
#define M_ 4096

typedef unsigned short u16;
typedef unsigned int u32;
typedef u16 u16x2 __attribute__((ext_vector_type(2)));
typedef u16 u16x4 __attribute__((ext_vector_type(4)));
typedef u16 u16x8 __attribute__((ext_vector_type(8)));
typedef __bf16 bf16x8 __attribute__((ext_vector_type(8)));
typedef float f32x4 __attribute__((ext_vector_type(4)));

#define AS1 __attribute__((address_space(1)))
#define AS3 __attribute__((address_space(3)))

__device__ __forceinline__ float b2f(u16 u) {
  union { unsigned int i; float f; } v; v.i = ((unsigned int)u) << 16; return v.f;
}
__device__ __forceinline__ u16 f2b(float f) {  // RNE, finite inputs
  unsigned int u = __float_as_uint(f);
  u += 0x7fffu + ((u >> 16) & 1u);
  return (u16)(u >> 16);
}
__device__ __forceinline__ bf16x8 u2b8(u16x8 v) {
  union { u16x8 u; bf16x8 b; } x; x.u = v; return x.b;
}

// --------------------------- small prep kernels ----------------------------

// interleaved {cos,sin} table: csT[t*32+i] = {cos(t*f_i), sin(t*f_i)}
__global__ __launch_bounds__(256) void rope_table_kernel(float2* csT) {
  int idx = blockIdx.x * 256 + threadIdx.x;    // T_*32 = 65536 threads
  int t = idx >> 5, i = idx & 31;
  float inv_freq = powf(10000.0f, -(float)(2 * i) / 64.0f);
  float ang = (float)t * inv_freq;
  csT[idx] = make_float2(cosf(ang), sinf(ang));
}

__global__ __launch_bounds__(256) void cast_x_kernel(const float* __restrict__ x,
                                                     u16* __restrict__ xb) {
  int i = blockIdx.x * 256 + threadIdx.x;      // M_*C_/4 threads
  float4 v = ((const float4*)x)[i];
  u16x4 r;
  r[0] = f2b(v.x); r[1] = f2b(v.y); r[2] = f2b(v.z); r[3] = f2b(v.w);
  ((u16x4*)xb)[i] = r;
}

// out[c][r] = bf16(in[r][c]);  R rows, Ccol cols in input. 32x32 tiles.
__global__ __launch_bounds__(256) void transpose_cast_kernel(const float* __restrict__ in,
                                                             u16* __restrict__ out,
                                                             int R, int Ccol) {
  __shared__ float tile[32][33];
  int c0 = blockIdx.x * 32, r0 = blockIdx.y * 32;
  int tx = threadIdx.x & 31, ty = threadIdx.x >> 5;   // ty = 0..7
  #pragma unroll
  for (int i = 0; i < 32; i += 8)
    tile[ty + i][tx] = in[(size_t)(r0 + ty + i) * Ccol + c0 + tx];
  __syncthreads();
  #pragma unroll
  for (int i = 0; i < 32; i += 8)
    out[(size_t)(c0 + ty + i) * R + r0 + tx] = f2b(tile[tx][ty + i]);
}

// ------------------------------- MFMA GEMM ---------------------------------
// C[M,N] = A[M,K] * Bt[N,K]^T, bf16 in. 128x128 tile, BK=32, 4 waves, 4x4
// 16x16x32 frags, global_load_lds(16) staging, 3-buffer distance-2 pipeline,
// T1 bijective XCD swizzle (grid % 8 == 0 for both dispatches).
// MODE 0: float out to Cm.
// MODE 2: QKV epilogue — RoPE(q,k via lane-pair shfl + csT) + scatter to
//         qr/kr/vr [B,H,T,D]; q pre-scaled by 0.125*log2(e).
template <int MODE>
__global__ __launch_bounds__(256) void gemm_bt_kernel(const u16* __restrict__ A,
                                                      const u16* __restrict__ Bt,
                                                      float* __restrict__ Cm,
                                                      u16* __restrict__ qr,
                                                      u16* __restrict__ kr,
                                                      u16* __restrict__ vrp,
                                                      const float2* __restrict__ csT,
                                                      int M, int N, int K) {
  __shared__ u16 sA[3][128 * 32];
  __shared__ u16 sB[3][128 * 32];
  const int tid = threadIdx.x;
  const int lane = tid & 63;
  const int wv = tid >> 6;
  const int wr = wv >> 1, wc = wv & 1;
  const int l16 = lane & 15, lq = lane >> 4;

  // T1 XCD swizzle: dispatch idx flat -> work item (flat%8)*cpx + flat/8.
  // XCD x (= flat%8) then owns a contiguous work range -> L2 panel reuse.
  const int gx = gridDim.x;
  const int nwg = gx * gridDim.y;
  const int flat = blockIdx.y * gx + blockIdx.x;
  const int swz = (flat & 7) * (nwg >> 3) + (flat >> 3);
  const int rowBase = (swz / gx) * 128;
  const int colBase = (swz % gx) * 128;

  f32x4 acc[4][4] = {};

  const int e0 = wv * 1024 + lane * 8;      // this lane's elem offset, chunk 0

#define GSTAGE(buf, kk)                                                          \
  {                                                                              \
    _Pragma("unroll")                                                            \
    for (int s = 0; s < 2; ++s) {                                                \
      int e = e0 + s * 512;                                                      \
      int r = e >> 5, ccc = e & 31;                                              \
      __builtin_amdgcn_global_load_lds(                                          \
          (const AS1 u32*)(A + (size_t)(rowBase + r) * K + (kk) + ccc),          \
          (AS3 u32*)&sA[buf][wv * 1024 + s * 512], 16, 0, 0);                    \
      __builtin_amdgcn_global_load_lds(                                          \
          (const AS1 u32*)(Bt + (size_t)(colBase + r) * K + (kk) + ccc),         \
          (AS3 u32*)&sB[buf][wv * 1024 + s * 512], 16, 0, 0);                    \
    }                                                                            \
  }

  const int NT = K >> 5;                 // K/32 tiles
  GSTAGE(0, 0);
  if (NT > 1) GSTAGE(1, 32);

  int cur = 0;
  for (int kt = 0; kt < NT; ++kt) {
    if (kt + 1 < NT) {
      asm volatile("s_waitcnt vmcnt(4)" ::: "memory");   // tile kt landed (own)
    } else {
      asm volatile("s_waitcnt vmcnt(0)" ::: "memory");   // final tile
    }
    __builtin_amdgcn_s_barrier();        // tile kt visible; k-1 reads done

    if (kt + 2 < NT) {
      int nb = cur + 2; if (nb >= 3) nb -= 3;
      GSTAGE(nb, (kt + 2) * 32);         // overlaps this iter's compute
    }

    bf16x8 af[4], bf[4];
    #pragma unroll
    for (int m = 0; m < 4; ++m)
      af[m] = u2b8(*(const u16x8*)&sA[cur][(wr * 64 + m * 16 + l16) * 32 + lq * 8]);
    #pragma unroll
    for (int n = 0; n < 4; ++n)
      bf[n] = u2b8(*(const u16x8*)&sB[cur][(wc * 64 + n * 16 + l16) * 32 + lq * 8]);
    __builtin_amdgcn_s_setprio(1);
    #pragma unroll
    for (int m = 0; m < 4; ++m)
      #pragma unroll
      for (int n = 0; n < 4; ++n)
        acc[m][n] = __builtin_amdgcn_mfma_f32_16x16x32_bf16(af[m], bf[n], acc[m][n], 0, 0, 0);
    __builtin_amdgcn_s_setprio(0);

    cur = (cur + 1 == 3) ? 0 : cur + 1;
  }
#undef GSTAGE

  // C/D layout (verified m89): col = lane&15, row = (lane>>4)*4 + reg
  if constexpr (MODE == 0) {
    #pragma unroll
    for (int m = 0; m < 4; ++m)
      #pragma unroll
      for (int n = 0; n < 4; ++n) {
        int row = rowBase + wr * 64 + m * 16 + lq * 4;
        int col = colBase + wc * 64 + n * 16 + l16;
        #pragma unroll
        for (int j = 0; j < 4; ++j)
          Cm[(size_t)(row + j) * N + col] = acc[m][n][j];
      }
  } else {
    // which: 0=q 1=k 2=v (block-uniform); head: uniform per (wave,n-range)
    const int which = colBase >> 10;
    const int head = ((colBase + wc * 64) >> 6) & 15;
    const float QSC = 0.125f * 1.44269504f;
    u16* const dst = (which == 0) ? qr : (which == 1) ? kr : vrp;
    #pragma unroll
    for (int m = 0; m < 4; ++m) {
      #pragma unroll
      for (int n = 0; n < 4; ++n) {
        const int d0 = n * 16 + l16;           // d within head (0..63)
        #pragma unroll
        for (int j = 0; j < 4; ++j) {
          int row = rowBase + wr * 64 + m * 16 + lq * 4 + j;
          int b = row >> 11, t = row & 2047;
          float v = acc[m][n][j];
          u16 outv;
          if (which == 2) {
            outv = f2b(v);
          } else {
            float p = __shfl_xor(v, 1);        // RoPE partner (d0^1)
            float2 cs = csT[t * 32 + (d0 >> 1)];
            float r = (l16 & 1) ? fmaf(p, cs.y, v * cs.x)    // odd:  xe*s + xo*c
                                : fmaf(-p, cs.y, v * cs.x);  // even: xe*c - xo*s
            if (which == 0) r *= QSC;
            outv = f2b(r);
          }
          dst[((size_t)(b * 16 + head) * 2048 + t) * 64 + d0] = outv;
        }
      }
    }
  }
}

// ------------------------- MFMA flash attention ----------------------------
// 16 q-rows/wave (R9 config), swapped QK^T, in-register P via k-slot
// permutation (V rows staged bit-permuted vrow=[b5 b2 b4 b3 b1 b0] so PV
// A-operand = own exp2'd registers), K staged by global_load_lds DMA into
// linear [64][64] with chunk swizzle (slot (r,c) holds chunk c^(r&7)),
// double buffer, T14 prefetch, ONE barrier per tile, launch_bounds(256,4).
// R13: causal work-pairing — block p runs segments qt={31-p, p} (33 tiles
// total, uniform across all 512 blocks -> zero drain tail).
__global__ __launch_bounds__(256, 4) void attn_mfma_kernel(const u16* __restrict__ qr,
                                                           const u16* __restrict__ kr,
                                                           const u16* __restrict__ vr,
                                                           u16* __restrict__ ao) {
  constexpr int LDVT = 72;
  __shared__ u16 sK[2][64 * 64];                 // linear, chunk-swizzled
  __shared__ u16 sVt[2][64 * LDVT];              // sVt[buf][d][k-slot]

  const int tid = threadIdx.x;
  const int lane = tid & 63;
  const int w = tid >> 6;
  const int l16 = lane & 15, lq = lane >> 4;
  const int bh = blockIdx.x;
  const int p = blockIdx.y;                      // 0..15
  const size_t hb = (size_t)bh * (T_ * D_);
  const int b = bh >> 4, h = bh & 15;

  // K DMA maps: wave w covers rows w*16 + s*8 + (lane>>3), chunk lane&7.
  const int krow0 = w * 16 + (lane >> 3);
  const int ksrc = ((lane & 7) ^ (lane >> 3)) * 8;   // elem offset in row
  // V staging maps (reg path)
  const int vkp = tid & 31;           // V slot-pair 0..31 (slots 2vkp, 2vkp+1)
  const int vdb = tid >> 5;           // V d-block 0..7
  const int vtr = ((vkp >> 4) & 1) * 32 + ((vkp >> 1) & 1) * 16 +
                  ((vkp >> 3) & 1) * 8 + ((vkp >> 2) & 1) * 4 + (vkp & 1) * 2;

  u16x8 rv0, rv1;
#define STAGEK(buf, k0s)                                                       \
  {                                                                            \
    _Pragma("unroll")                                                          \
    for (int s = 0; s < 2; ++s)                                                \
      __builtin_amdgcn_global_load_lds(                                        \
          (const AS1 u32*)(kr + hb + (size_t)((k0s) + krow0 + s * 8) * 64 + ksrc), \
          (AS3 u32*)&sK[buf][(w * 16 + s * 8) * 64], 16, 0, 0);                \
  }
#define LOADV(k0s)                                                             \
  {                                                                            \
    rv0 = *(const u16x8*)(vr + hb + (size_t)((k0s) + vtr) * 64 + vdb * 8);     \
    rv1 = *(const u16x8*)(vr + hb + (size_t)((k0s) + vtr + 1) * 64 + vdb * 8); \
  }
#define WRITEV(buf)                                                            \
  {                                                                            \
    _Pragma("unroll")                                                          \
    for (int u = 0; u < 8; ++u) {                                              \
      u16x2 pk; pk[0] = rv0[u]; pk[1] = rv1[u];                                \
      *(u16x2*)&sVt[buf][(vdb * 8 + u) * LDVT + 2 * vkp] = pk;                 \
    }                                                                          \
  }

  for (int seg = 0; seg < 2; ++seg) {
    const int qt = (seg == 0) ? (31 - p) : p;    // pair: (31-p) + (p) = 33 tiles
    const int qbase = qt * 64;
    const int nt = qt + 1;

    // Q frags (pre-scaled bf16): rows qbase + w*16 + l16
    bf16x8 qv[2];
    #pragma unroll
    for (int dc = 0; dc < 2; ++dc) {
      int row = qbase + w * 16 + l16;
      qv[dc] = u2b8(*(const u16x8*)(qr + hb + (size_t)row * 64 + dc * 32 + lq * 8));
    }

    f32x4 o[4] = {};              // o[dt]: O[q=lq*4+j][d=dt*16+l16]
    float mrow = -1e30f;          // running max (log2 domain), row q=l16
    float lrow = 0.0f;            // per-lane partial denom, row q=l16

    STAGEK(0, 0);
    LOADV(0);
    WRITEV(0);
    __syncthreads();              // drains vmcnt (K DMA) + LDS writes

    int cur = 0;
    for (int it = 0; it < nt; ++it) {
      const int k0 = it * 64;
      const bool more = (it + 1 < nt);
      if (more) {
        STAGEK(cur ^ 1, k0 + 64);        // async DMA into other buffer
        LOADV(k0 + 64);                  // V prefetch into regs (T14)
      }

      // ---- QK^T (swapped): accs[kt][j] = S[q=l16][slot k0+kt*16+lq*4+j]
      f32x4 accs[4] = {};
      __builtin_amdgcn_s_setprio(1);
      #pragma unroll
      for (int kt = 0; kt < 4; ++kt) {
        int chy = ((lq) ^ (l16 & 7)) * 8;        // dc=0 chunk
        int chz = ((4 + lq) ^ (l16 & 7)) * 8;    // dc=1 chunk
        bf16x8 kf0 = u2b8(*(const u16x8*)&sK[cur][(kt * 16 + l16) * 64 + chy]);
        bf16x8 kf1 = u2b8(*(const u16x8*)&sK[cur][(kt * 16 + l16) * 64 + chz]);
        accs[kt] = __builtin_amdgcn_mfma_f32_16x16x32_bf16(kf0, qv[0], accs[kt], 0, 0, 0);
        accs[kt] = __builtin_amdgcn_mfma_f32_16x16x32_bf16(kf1, qv[1], accs[kt], 0, 0, 0);
      }
      __builtin_amdgcn_s_setprio(0);

      const int qrow = qbase + w * 16 + l16;
      if (k0 + 63 > qbase + w * 16) {      // wave-uniform: diagonal tile only
        #pragma unroll
        for (int kt = 0; kt < 4; ++kt)
          #pragma unroll
          for (int j = 0; j < 4; ++j)
            if (k0 + kt * 16 + lq * 4 + j > qrow) accs[kt][j] = -1e30f;
      }
      // row max for q=l16: depth-4 tree + 2 shfl (k spread across lq groups)
      float m0 = fmaxf(fmaxf(accs[0][0], accs[0][1]), fmaxf(accs[0][2], accs[0][3]));
      float m1 = fmaxf(fmaxf(accs[1][0], accs[1][1]), fmaxf(accs[1][2], accs[1][3]));
      float m2 = fmaxf(fmaxf(accs[2][0], accs[2][1]), fmaxf(accs[2][2], accs[2][3]));
      float m3 = fmaxf(fmaxf(accs[3][0], accs[3][1]), fmaxf(accs[3][2], accs[3][3]));
      float mx = fmaxf(fmaxf(m0, m1), fmaxf(m2, m3));
      mx = fmaxf(mx, __shfl_xor(mx, 16));
      mx = fmaxf(mx, __shfl_xor(mx, 32));

      if (!__all(mx <= mrow)) {            // defer-max: exact skip when no new max
        float mnew = fmaxf(mrow, mx);
        float corr = __builtin_amdgcn_exp2f(mrow - mnew);   // row q=l16
        lrow *= corr;
        mrow = mnew;
        // broadcast corr into D-row space (q=lq*4+j) before scaling O
        f32x4 corrv;
        #pragma unroll
        for (int j = 0; j < 4; ++j) corrv[j] = __shfl(corr, lq * 4 + j);
        #pragma unroll
        for (int dt = 0; dt < 4; ++dt) o[dt] *= corrv;
      }
      const float mu = mrow;
      // exp2 + pack: pb[kc][u] : u<4 <- slot kt=2kc, u>=4 <- kt=2kc+1
      bf16x8 pb[2];
      float lsum = 0.0f;
      #pragma unroll
      for (int kt = 0; kt < 4; ++kt) {
        #pragma unroll
        for (int j = 0; j < 4; ++j) {
          float pw = __builtin_amdgcn_exp2f(accs[kt][j] - mu);
          lsum += pw;
          pb[kt >> 1][(kt & 1) * 4 + j] = (__bf16)pw;   // -> v_cvt_pk_bf16_f32
        }
      }
      lrow += lsum;

      // ---- PV: A-operand = own registers (slot perm); B from sVt ----
      __builtin_amdgcn_s_setprio(1);
      #pragma unroll
      for (int kc = 0; kc < 2; ++kc) {
        #pragma unroll
        for (int dt = 0; dt < 4; ++dt) {
          bf16x8 vt = u2b8(*(const u16x8*)&sVt[cur][(dt * 16 + l16) * LDVT + kc * 32 + lq * 8]);
          o[dt] = __builtin_amdgcn_mfma_f32_16x16x32_bf16(pb[kc], vt, o[dt], 0, 0, 0);
        }
      }
      __builtin_amdgcn_s_setprio(0);

      if (more) WRITEV(cur ^ 1);           // V^T into other buffer (reads were cur)
      __syncthreads();                     // one barrier/tile; drains K DMA too
      cur ^= 1;
    }

    // finalize: full row denom in l16-space, broadcast 1/l into D-row space.
    float l = lrow;
    l += __shfl_xor(l, 16);
    l += __shfl_xor(l, 32);
    float linv = 1.0f / l;
    #pragma unroll
    for (int j = 0; j < 4; ++j) {
      float lj = __shfl(linv, lq * 4 + j);   // lane r (r<16) holds row r's denom
      int row = qbase + w * 16 + lq * 4 + j;
      u16* orow = ao + ((size_t)(b * T_ + row)) * C_ + h * 64;
      #pragma unroll
      for (int dt = 0; dt < 4; ++dt)
        orow[dt * 16 + l16] = f2b(o[dt][j] * lj);
    }
    // next segment's prologue staging is safe: the loop's trailing
    // __syncthreads() already separated all reads of sK/sVt from overwrite.
  }
}

// ------------------------------- launcher ----------------------------------
// ws layout (bytes):                              size
//   xb     @ 0           bf16 x           8,388,608
//   wqkvT  @ 8388608     bf16 w_qkv^T     6,291,456
//   woutT  @ 14680064    bf16 w_out^T     2,097,152
//   qr     @ 41943040    bf16 [B,H,T,D]   8,388,608
//   kr     @ 50331648                     8,388,608
//   vr     @ 58720256                     8,388,608
//   ao     @ 67108864    bf16 attn out    8,388,608
//   csT    @ 75497472    f32x2 rope tbl     524,288
extern "C" void kernel_launch(void* const* d_in, const int* in_sizes, int n_in,
                              void* d_out, int out_size, void* d_ws, size_t ws_size,
                              hipStream_t stream) {
  const float* x     = (const float*)d_in[0];
  const float* w_qkv = (const float*)d_in[1];
  const float* w_out = (const float*)d_in[2];
  float* out = (float*)d_out;
  char* ws = (char*)d_ws;

  u16* xb     = (u16*)(ws + 0);
  u16* wqkvT  = (u16*)(ws + 8388608);
  u16* woutT  = (u16*)(ws + 14680064);
  u16* qr     = (u16*)(ws + 41943040);
  u16* kr     = (u16*)(ws + 50331648);
  u16* vr     = (u16*)(ws + 58720256);
  u16* ao     = (u16*)(ws + 67108864);
  float2* csT = (float2*)(ws + 75497472);

  rope_table_kernel<<<256, 256, 0, stream>>>(csT);
  cast_x_kernel<<<4096, 256, 0, stream>>>(x, xb);
  transpose_cast_kernel<<<dim3(96, 32), 256, 0, stream>>>(w_qkv, wqkvT, C_, F_);
  transpose_cast_kernel<<<dim3(32, 32), 256, 0, stream>>>(w_out, woutT, C_, C_);
  gemm_bt_kernel<2><<<dim3(F_ / 128, M_ / 128), 256, 0, stream>>>(
      xb, wqkvT, nullptr, qr, kr, vr, (const float2*)csT, M_, F_, C_);
  attn_mfma_kernel<<<dim3(B_ * H_, 16), 256, 0, stream>>>(qr, kr, vr, ao);
  gemm_bt_kernel<0><<<dim3(C_ / 128, M_ / 128), 256, 0, stream>>>(
      ao, woutT, out, nullptr, nullptr, nullptr, nullptr, M_, C_, C_);
}

// Round 15
// 126.179 us; speedup vs baseline: 1.1829x; 1.1011x over previous
//
#include <hip/hip_runtime.h>
#include <stdint.h>

// ---------------------------------------------------------------------------
// MultiHeadSelfAttention: x(2,2048,1024) fp32, w_qkv(1024,3072), w_out(1024,1024)
// R14: (a) attn reverted to R9 config (R13 pairing: uniform work but 2 blocks/
// CU < 4 -> occ 20%, slower; latency-bound kernel needs resident blocks).
// (b) all 4 prep kernels fused into ONE (block-range split: cast_x | transpose
// w_qkv | transpose w_out | rope_table) — removes 3 dispatch gaps, shares CUs.
// GEMMs unchanged (128^2 distance-2 + XCD swizzle; 2-phase ceiling documented).
// ---------------------------------------------------------------------------

#define B_ 2
#define T_ 2048
#define C_ 1024
#define H_ 16
#define D_ 64
#define F_ 3072
#define M_ 4096

typedef unsigned short u16;
typedef unsigned int u32;
typedef u16 u16x2 __attribute__((ext_vector_type(2)));
typedef u16 u16x4 __attribute__((ext_vector_type(4)));
typedef u16 u16x8 __attribute__((ext_vector_type(8)));
typedef __bf16 bf16x8 __attribute__((ext_vector_type(8)));
typedef float f32x4 __attribute__((ext_vector_type(4)));

#define AS1 __attribute__((address_space(1)))
#define AS3 __attribute__((address_space(3)))

__device__ __forceinline__ float b2f(u16 u) {
  union { unsigned int i; float f; } v; v.i = ((unsigned int)u) << 16; return v.f;
}
__device__ __forceinline__ u16 f2b(float f) {  // RNE, finite inputs
  unsigned int u = __float_as_uint(f);
  u += 0x7fffu + ((u >> 16) & 1u);
  return (u16)(u >> 16);
}
__device__ __forceinline__ bf16x8 u2b8(u16x8 v) {
  union { u16x8 u; bf16x8 b; } x; x.u = v; return x.b;
}

// ----------------------------- fused prep kernel ---------------------------
// grid 8448 x 256: [0,4096) cast_x | [4096,7168) transpose w_qkv |
// [7168,8192) transpose w_out | [8192,8448) rope cos/sin table.
__global__ __launch_bounds__(256) void prep_kernel(const float* __restrict__ x,
                                                   const float* __restrict__ w_qkv,
                                                   const float* __restrict__ w_out,
                                                   u16* __restrict__ xb,
                                                   u16* __restrict__ wqkvT,
                                                   u16* __restrict__ woutT,
                                                   float2* __restrict__ csT) {
  __shared__ float tile[32][33];
  const int bid = blockIdx.x;
  const int tid = threadIdx.x;

  if (bid < 4096) {                       // ---- cast_x: fp32 -> bf16 ----
    int i = bid * 256 + tid;              // M_*C_/4 elems of float4
    float4 v = ((const float4*)x)[i];
    u16x4 r;
    r[0] = f2b(v.x); r[1] = f2b(v.y); r[2] = f2b(v.z); r[3] = f2b(v.w);
    ((u16x4*)xb)[i] = r;
  } else if (bid < 8192) {                // ---- transpose_cast w_qkv / w_out
    const float* in;  u16* out;  int R, Ccol, b;
    if (bid < 7168) { in = w_qkv; out = wqkvT; R = C_; Ccol = F_; b = bid - 4096; }
    else            { in = w_out; out = woutT; R = C_; Ccol = C_; b = bid - 7168; }
    int nbx = Ccol / 32;
    int c0 = (b % nbx) * 32, r0 = (b / nbx) * 32;
    int tx = tid & 31, ty = tid >> 5;     // ty = 0..7
    #pragma unroll
    for (int i = 0; i < 32; i += 8)
      tile[ty + i][tx] = in[(size_t)(r0 + ty + i) * Ccol + c0 + tx];
    __syncthreads();
    #pragma unroll
    for (int i = 0; i < 32; i += 8)
      out[(size_t)(c0 + ty + i) * R + r0 + tx] = f2b(tile[tx][ty + i]);
  } else {                                // ---- rope table ----
    int idx = (bid - 8192) * 256 + tid;   // T_*32 entries
    int t = idx >> 5, i = idx & 31;
    float inv_freq = powf(10000.0f, -(float)(2 * i) / 64.0f);
    float ang = (float)t * inv_freq;
    csT[idx] = make_float2(cosf(ang), sinf(ang));
  }
}

// ------------------------------- MFMA GEMM ---------------------------------
// C[M,N] = A[M,K] * Bt[N,K]^T, bf16 in. 128x128 tile, BK=32, 4 waves, 4x4
// 16x16x32 frags, global_load_lds(16) staging, 3-buffer distance-2 pipeline,
// T1 bijective XCD swizzle (grid % 8 == 0 for both dispatches).
// MODE 0: float out to Cm.
// MODE 2: QKV epilogue — RoPE(q,k via lane-pair shfl + csT) + scatter to
//         qr/kr/vr [B,H,T,D]; q pre-scaled by 0.125*log2(e).
template <int MODE>
__global__ __launch_bounds__(256) void gemm_bt_kernel(const u16* __restrict__ A,
                                                      const u16* __restrict__ Bt,
                                                      float* __restrict__ Cm,
                                                      u16* __restrict__ qr,
                                                      u16* __restrict__ kr,
                                                      u16* __restrict__ vrp,
                                                      const float2* __restrict__ csT,
                                                      int M, int N, int K) {
  __shared__ u16 sA[3][128 * 32];
  __shared__ u16 sB[3][128 * 32];
  const int tid = threadIdx.x;
  const int lane = tid & 63;
  const int wv = tid >> 6;
  const int wr = wv >> 1, wc = wv & 1;
  const int l16 = lane & 15, lq = lane >> 4;

  // T1 XCD swizzle: dispatch idx flat -> work item (flat%8)*cpx + flat/8.
  const int gx = gridDim.x;
  const int nwg = gx * gridDim.y;
  const int flat = blockIdx.y * gx + blockIdx.x;
  const int swz = (flat & 7) * (nwg >> 3) + (flat >> 3);
  const int rowBase = (swz / gx) * 128;
  const int colBase = (swz % gx) * 128;

  f32x4 acc[4][4] = {};

  const int e0 = wv * 1024 + lane * 8;      // this lane's elem offset, chunk 0

#define GSTAGE(buf, kk)                                                          \
  {                                                                              \
    _Pragma("unroll")                                                            \
    for (int s = 0; s < 2; ++s) {                                                \
      int e = e0 + s * 512;                                                      \
      int r = e >> 5, ccc = e & 31;                                              \
      __builtin_amdgcn_global_load_lds(                                          \
          (const AS1 u32*)(A + (size_t)(rowBase + r) * K + (kk) + ccc),          \
          (AS3 u32*)&sA[buf][wv * 1024 + s * 512], 16, 0, 0);                    \
      __builtin_amdgcn_global_load_lds(                                          \
          (const AS1 u32*)(Bt + (size_t)(colBase + r) * K + (kk) + ccc),         \
          (AS3 u32*)&sB[buf][wv * 1024 + s * 512], 16, 0, 0);                    \
    }                                                                            \
  }

  const int NT = K >> 5;                 // K/32 tiles
  GSTAGE(0, 0);
  if (NT > 1) GSTAGE(1, 32);

  int cur = 0;
  for (int kt = 0; kt < NT; ++kt) {
    if (kt + 1 < NT) {
      asm volatile("s_waitcnt vmcnt(4)" ::: "memory");   // tile kt landed (own)
    } else {
      asm volatile("s_waitcnt vmcnt(0)" ::: "memory");   // final tile
    }
    __builtin_amdgcn_s_barrier();        // tile kt visible; k-1 reads done

    if (kt + 2 < NT) {
      int nb = cur + 2; if (nb >= 3) nb -= 3;
      GSTAGE(nb, (kt + 2) * 32);         // overlaps this iter's compute
    }

    bf16x8 af[4], bf[4];
    #pragma unroll
    for (int m = 0; m < 4; ++m)
      af[m] = u2b8(*(const u16x8*)&sA[cur][(wr * 64 + m * 16 + l16) * 32 + lq * 8]);
    #pragma unroll
    for (int n = 0; n < 4; ++n)
      bf[n] = u2b8(*(const u16x8*)&sB[cur][(wc * 64 + n * 16 + l16) * 32 + lq * 8]);
    __builtin_amdgcn_s_setprio(1);
    #pragma unroll
    for (int m = 0; m < 4; ++m)
      #pragma unroll
      for (int n = 0; n < 4; ++n)
        acc[m][n] = __builtin_amdgcn_mfma_f32_16x16x32_bf16(af[m], bf[n], acc[m][n], 0, 0, 0);
    __builtin_amdgcn_s_setprio(0);

    cur = (cur + 1 == 3) ? 0 : cur + 1;
  }
#undef GSTAGE

  // C/D layout (verified m89): col = lane&15, row = (lane>>4)*4 + reg
  if constexpr (MODE == 0) {
    #pragma unroll
    for (int m = 0; m < 4; ++m)
      #pragma unroll
      for (int n = 0; n < 4; ++n) {
        int row = rowBase + wr * 64 + m * 16 + lq * 4;
        int col = colBase + wc * 64 + n * 16 + l16;
        #pragma unroll
        for (int j = 0; j < 4; ++j)
          Cm[(size_t)(row + j) * N + col] = acc[m][n][j];
      }
  } else {
    // which: 0=q 1=k 2=v (block-uniform); head: uniform per (wave,n-range)
    const int which = colBase >> 10;
    const int head = ((colBase + wc * 64) >> 6) & 15;
    const float QSC = 0.125f * 1.44269504f;
    u16* const dst = (which == 0) ? qr : (which == 1) ? kr : vrp;
    #pragma unroll
    for (int m = 0; m < 4; ++m) {
      #pragma unroll
      for (int n = 0; n < 4; ++n) {
        const int d0 = n * 16 + l16;           // d within head (0..63)
        #pragma unroll
        for (int j = 0; j < 4; ++j) {
          int row = rowBase + wr * 64 + m * 16 + lq * 4 + j;
          int b = row >> 11, t = row & 2047;
          float v = acc[m][n][j];
          u16 outv;
          if (which == 2) {
            outv = f2b(v);
          } else {
            float p = __shfl_xor(v, 1);        // RoPE partner (d0^1)
            float2 cs = csT[t * 32 + (d0 >> 1)];
            float r = (l16 & 1) ? fmaf(p, cs.y, v * cs.x)    // odd:  xe*s + xo*c
                                : fmaf(-p, cs.y, v * cs.x);  // even: xe*c - xo*s
            if (which == 0) r *= QSC;
            outv = f2b(r);
          }
          dst[((size_t)(b * 16 + head) * 2048 + t) * 64 + d0] = outv;
        }
      }
    }
  }
}

// ------------------------- MFMA flash attention ----------------------------
// R9 config (proven fastest): 16 q-rows/wave, grid (32,32) descending, swapped
// QK^T, in-register P via k-slot permutation (V rows staged bit-permuted
// vrow=[b5 b2 b4 b3 b1 b0] so PV A-operand = own exp2'd registers), K staged
// by global_load_lds DMA into linear [64][64] with chunk swizzle (slot (r,c)
// holds chunk c^(r&7)), double buffer, T14 prefetch, ONE barrier per tile.
__global__ __launch_bounds__(256, 4) void attn_mfma_kernel(const u16* __restrict__ qr,
                                                           const u16* __restrict__ kr,
                                                           const u16* __restrict__ vr,
                                                           u16* __restrict__ ao) {
  constexpr int LDVT = 72;
  __shared__ u16 sK[2][64 * 64];                 // linear, chunk-swizzled
  __shared__ u16 sVt[2][64 * LDVT];              // sVt[buf][d][k-slot]

  const int tid = threadIdx.x;
  const int lane = tid & 63;
  const int w = tid >> 6;
  const int l16 = lane & 15, lq = lane >> 4;
  const int bh = blockIdx.x;
  const int qt = (int)gridDim.y - 1 - (int)blockIdx.y;   // long blocks first
  const int qbase = qt * 64;
  const size_t hb = (size_t)bh * (T_ * D_);

  // Q frags (pre-scaled bf16): rows qbase + w*16 + l16
  bf16x8 qv[2];
  #pragma unroll
  for (int dc = 0; dc < 2; ++dc) {
    int row = qbase + w * 16 + l16;
    qv[dc] = u2b8(*(const u16x8*)(qr + hb + (size_t)row * 64 + dc * 32 + lq * 8));
  }

  f32x4 o[4] = {};              // o[dt]: O[q=lq*4+j][d=dt*16+l16]
  float mrow = -1e30f;          // running max (log2 domain), row q=l16
  float lrow = 0.0f;            // per-lane partial denom, row q=l16

  // K DMA maps: wave w covers rows w*16 + s*8 + (lane>>3), chunk lane&7.
  const int krow0 = w * 16 + (lane >> 3);
  const int ksrc = ((lane & 7) ^ (lane >> 3)) * 8;   // elem offset in row
  // V staging maps (reg path)
  const int vkp = tid & 31;           // V slot-pair 0..31 (slots 2vkp, 2vkp+1)
  const int vdb = tid >> 5;           // V d-block 0..7
  const int vtr = ((vkp >> 4) & 1) * 32 + ((vkp >> 1) & 1) * 16 +
                  ((vkp >> 3) & 1) * 8 + ((vkp >> 2) & 1) * 4 + (vkp & 1) * 2;

  u16x8 rv0, rv1;
#define STAGEK(buf, k0s)                                                       \
  {                                                                            \
    _Pragma("unroll")                                                          \
    for (int s = 0; s < 2; ++s)                                                \
      __builtin_amdgcn_global_load_lds(                                        \
          (const AS1 u32*)(kr + hb + (size_t)((k0s) + krow0 + s * 8) * 64 + ksrc), \
          (AS3 u32*)&sK[buf][(w * 16 + s * 8) * 64], 16, 0, 0);                \
  }
#define LOADV(k0s)                                                             \
  {                                                                            \
    rv0 = *(const u16x8*)(vr + hb + (size_t)((k0s) + vtr) * 64 + vdb * 8);     \
    rv1 = *(const u16x8*)(vr + hb + (size_t)((k0s) + vtr + 1) * 64 + vdb * 8); \
  }
#define WRITEV(buf)                                                            \
  {                                                                            \
    _Pragma("unroll")                                                          \
    for (int u = 0; u < 8; ++u) {                                              \
      u16x2 pk; pk[0] = rv0[u]; pk[1] = rv1[u];                                \
      *(u16x2*)&sVt[buf][(vdb * 8 + u) * LDVT + 2 * vkp] = pk;                 \
    }                                                                          \
  }

  STAGEK(0, 0);
  LOADV(0);
  WRITEV(0);
  __syncthreads();               // drains vmcnt (K DMA) + LDS writes

  const int nt = qt + 1;
  int cur = 0;
  for (int it = 0; it < nt; ++it) {
    const int k0 = it * 64;
    const bool more = (it + 1 < nt);
    if (more) {
      STAGEK(cur ^ 1, k0 + 64);        // async DMA into other buffer
      LOADV(k0 + 64);                  // V prefetch into regs (T14)
    }

    // ---- QK^T (swapped): accs[kt][j] = S[q=l16][slot k0+kt*16+lq*4+j]
    f32x4 accs[4] = {};
    __builtin_amdgcn_s_setprio(1);
    #pragma unroll
    for (int kt = 0; kt < 4; ++kt) {
      int chy = ((lq) ^ (l16 & 7)) * 8;        // dc=0 chunk
      int chz = ((4 + lq) ^ (l16 & 7)) * 8;    // dc=1 chunk
      bf16x8 kf0 = u2b8(*(const u16x8*)&sK[cur][(kt * 16 + l16) * 64 + chy]);
      bf16x8 kf1 = u2b8(*(const u16x8*)&sK[cur][(kt * 16 + l16) * 64 + chz]);
      accs[kt] = __builtin_amdgcn_mfma_f32_16x16x32_bf16(kf0, qv[0], accs[kt], 0, 0, 0);
      accs[kt] = __builtin_amdgcn_mfma_f32_16x16x32_bf16(kf1, qv[1], accs[kt], 0, 0, 0);
    }
    __builtin_amdgcn_s_setprio(0);

    const int qrow = qbase + w * 16 + l16;
    if (k0 + 63 > qbase + w * 16) {      // wave-uniform: diagonal tile only
      #pragma unroll
      for (int kt = 0; kt < 4; ++kt)
        #pragma unroll
        for (int j = 0; j < 4; ++j)
          if (k0 + kt * 16 + lq * 4 + j > qrow) accs[kt][j] = -1e30f;
    }
    // row max for q=l16: depth-4 tree + 2 shfl (k spread across lq groups)
    float m0 = fmaxf(fmaxf(accs[0][0], accs[0][1]), fmaxf(accs[0][2], accs[0][3]));
    float m1 = fmaxf(fmaxf(accs[1][0], accs[1][1]), fmaxf(accs[1][2], accs[1][3]));
    float m2 = fmaxf(fmaxf(accs[2][0], accs[2][1]), fmaxf(accs[2][2], accs[2][3]));
    float m3 = fmaxf(fmaxf(accs[3][0], accs[3][1]), fmaxf(accs[3][2], accs[3][3]));
    float mx = fmaxf(fmaxf(m0, m1), fmaxf(m2, m3));
    mx = fmaxf(mx, __shfl_xor(mx, 16));
    mx = fmaxf(mx, __shfl_xor(mx, 32));

    if (!__all(mx <= mrow)) {            // defer-max: exact skip when no new max
      float mnew = fmaxf(mrow, mx);
      float corr = __builtin_amdgcn_exp2f(mrow - mnew);   // row q=l16
      lrow *= corr;
      mrow = mnew;
      // broadcast corr into D-row space (q=lq*4+j) before scaling O
      f32x4 corrv;
      #pragma unroll
      for (int j = 0; j < 4; ++j) corrv[j] = __shfl(corr, lq * 4 + j);
      #pragma unroll
      for (int dt = 0; dt < 4; ++dt) o[dt] *= corrv;
    }
    const float mu = mrow;
    // exp2 + pack: pb[kc][u] : u<4 <- slot kt=2kc, u>=4 <- kt=2kc+1
    bf16x8 pb[2];
    float lsum = 0.0f;
    #pragma unroll
    for (int kt = 0; kt < 4; ++kt) {
      #pragma unroll
      for (int j = 0; j < 4; ++j) {
        float p = __builtin_amdgcn_exp2f(accs[kt][j] - mu);
        lsum += p;
        pb[kt >> 1][(kt & 1) * 4 + j] = (__bf16)p;   // -> v_cvt_pk_bf16_f32
      }
    }
    lrow += lsum;

    // ---- PV: A-operand = own registers (slot perm); B from sVt ----
    __builtin_amdgcn_s_setprio(1);
    #pragma unroll
    for (int kc = 0; kc < 2; ++kc) {
      #pragma unroll
      for (int dt = 0; dt < 4; ++dt) {
        bf16x8 vt = u2b8(*(const u16x8*)&sVt[cur][(dt * 16 + l16) * LDVT + kc * 32 + lq * 8]);
        o[dt] = __builtin_amdgcn_mfma_f32_16x16x32_bf16(pb[kc], vt, o[dt], 0, 0, 0);
      }
    }
    __builtin_amdgcn_s_setprio(0);

    if (more) WRITEV(cur ^ 1);           // V^T into other buffer (reads were cur)
    __syncthreads();                     // one barrier/tile; drains K DMA too
    cur ^= 1;
  }

  // finalize: full row denom in l16-space, broadcast 1/l into D-row space.
  const int b = bh >> 4, h = bh & 15;
  float l = lrow;
  l += __shfl_xor(l, 16);
  l += __shfl_xor(l, 32);
  float linv = 1.0f / l;
  #pragma unroll
  for (int j = 0; j < 4; ++j) {
    float lj = __shfl(linv, lq * 4 + j);   // lane r (r<16) holds row r's denom
    int row = qbase + w * 16 + lq * 4 + j;
    u16* orow = ao + ((size_t)(b * T_ + row)) * C_ + h * 64;
    #pragma unroll
    for (int dt = 0; dt < 4; ++dt)
      orow[dt * 16 + l16] = f2b(o[dt][j] * lj);
  }
}

// ------------------------------- launcher ----------------------------------
// ws layout (bytes):                              size
//   xb     @ 0           bf16 x           8,388,608
//   wqkvT  @ 8388608     bf16 w_qkv^T     6,291,456
//   woutT  @ 14680064    bf16 w_out^T     2,097,152
//   qr     @ 41943040    bf16 [B,H,T,D]   8,388,608
//   kr     @ 50331648                     8,388,608
//   vr     @ 58720256                     8,388,608
//   ao     @ 67108864    bf16 attn out    8,388,608
//   csT    @ 75497472    f32x2 rope tbl     524,288
extern "C" void kernel_launch(void* const* d_in, const int* in_sizes, int n_in,
                              void* d_out, int out_size, void* d_ws, size_t ws_size,
                              hipStream_t stream) {
  const float* x     = (const float*)d_in[0];
  const float* w_qkv = (const float*)d_in[1];
  const float* w_out = (const float*)d_in[2];
  float* out = (float*)d_out;
  char* ws = (char*)d_ws;

  u16* xb     = (u16*)(ws + 0);
  u16* wqkvT  = (u16*)(ws + 8388608);
  u16* woutT  = (u16*)(ws + 14680064);
  u16* qr     = (u16*)(ws + 41943040);
  u16* kr     = (u16*)(ws + 50331648);
  u16* vr     = (u16*)(ws + 58720256);
  u16* ao     = (u16*)(ws + 67108864);
  float2* csT = (float2*)(ws + 75497472);

  prep_kernel<<<8448, 256, 0, stream>>>(x, w_qkv, w_out, xb, wqkvT, woutT, csT);
  gemm_bt_kernel<2><<<dim3(F_ / 128, M_ / 128), 256, 0, stream>>>(
      xb, wqkvT, nullptr, qr, kr, vr, (const float2*)csT, M_, F_, C_);
  attn_mfma_kernel<<<dim3(B_ * H_, T_ / 64), 256, 0, stream>>>(qr, kr, vr, ao);
  gemm_bt_kernel<0><<<dim3(C_ / 128, M_ / 128), 256, 0, stream>>>(
      ao, woutT, out, nullptr, nullptr, nullptr, nullptr, M_, C_, C_);
}

// Round 16
// 121.487 us; speedup vs baseline: 1.2286x; 1.0386x over previous
//
#include <hip/hip_runtime.h>
#include <stdint.h>

// ---------------------------------------------------------------------------
// MultiHeadSelfAttention: x(2,2048,1024) fp32, w_qkv(1024,3072), w_out(1024,1024)
// R15: out-proj was running at 1 block/CU (grid 256 = (1024/128)x(4096/128))
// -> every barrier exposed, ~17us. New 64x64-tile variant of the same proven
// distance-2 pipeline: grid (16,64)=1024 = 4 blocks/CU, vmcnt(2) (1 DMA per
// thread per operand per tile), LDS 24KB. qkv/attn/prep unchanged (R14 = best).
// ---------------------------------------------------------------------------

#define B_ 2
#define T_ 2048
#define C_ 1024
#define H_ 16
#define D_ 64
#define F_ 3072
#define M_ 4096

typedef unsigned short u16;
typedef unsigned int u32;
typedef u16 u16x2 __attribute__((ext_vector_type(2)));
typedef u16 u16x4 __attribute__((ext_vector_type(4)));
typedef u16 u16x8 __attribute__((ext_vector_type(8)));
typedef __bf16 bf16x8 __attribute__((ext_vector_type(8)));
typedef float f32x4 __attribute__((ext_vector_type(4)));

#define AS1 __attribute__((address_space(1)))
#define AS3 __attribute__((address_space(3)))

__device__ __forceinline__ float b2f(u16 u) {
  union { unsigned int i; float f; } v; v.i = ((unsigned int)u) << 16; return v.f;
}
__device__ __forceinline__ u16 f2b(float f) {  // RNE, finite inputs
  unsigned int u = __float_as_uint(f);
  u += 0x7fffu + ((u >> 16) & 1u);
  return (u16)(u >> 16);
}
__device__ __forceinline__ bf16x8 u2b8(u16x8 v) {
  union { u16x8 u; bf16x8 b; } x; x.u = v; return x.b;
}

// ----------------------------- fused prep kernel ---------------------------
// grid 8448 x 256: [0,4096) cast_x | [4096,7168) transpose w_qkv |
// [7168,8192) transpose w_out | [8192,8448) rope cos/sin table.
__global__ __launch_bounds__(256) void prep_kernel(const float* __restrict__ x,
                                                   const float* __restrict__ w_qkv,
                                                   const float* __restrict__ w_out,
                                                   u16* __restrict__ xb,
                                                   u16* __restrict__ wqkvT,
                                                   u16* __restrict__ woutT,
                                                   float2* __restrict__ csT) {
  __shared__ float tile[32][33];
  const int bid = blockIdx.x;
  const int tid = threadIdx.x;

  if (bid < 4096) {                       // ---- cast_x: fp32 -> bf16 ----
    int i = bid * 256 + tid;              // M_*C_/4 elems of float4
    float4 v = ((const float4*)x)[i];
    u16x4 r;
    r[0] = f2b(v.x); r[1] = f2b(v.y); r[2] = f2b(v.z); r[3] = f2b(v.w);
    ((u16x4*)xb)[i] = r;
  } else if (bid < 8192) {                // ---- transpose_cast w_qkv / w_out
    const float* in;  u16* out;  int R, Ccol, b;
    if (bid < 7168) { in = w_qkv; out = wqkvT; R = C_; Ccol = F_; b = bid - 4096; }
    else            { in = w_out; out = woutT; R = C_; Ccol = C_; b = bid - 7168; }
    int nbx = Ccol / 32;
    int c0 = (b % nbx) * 32, r0 = (b / nbx) * 32;
    int tx = tid & 31, ty = tid >> 5;     // ty = 0..7
    #pragma unroll
    for (int i = 0; i < 32; i += 8)
      tile[ty + i][tx] = in[(size_t)(r0 + ty + i) * Ccol + c0 + tx];
    __syncthreads();
    #pragma unroll
    for (int i = 0; i < 32; i += 8)
      out[(size_t)(c0 + ty + i) * R + r0 + tx] = f2b(tile[tx][ty + i]);
  } else {                                // ---- rope table ----
    int idx = (bid - 8192) * 256 + tid;   // T_*32 entries
    int t = idx >> 5, i = idx & 31;
    float inv_freq = powf(10000.0f, -(float)(2 * i) / 64.0f);
    float ang = (float)t * inv_freq;
    csT[idx] = make_float2(cosf(ang), sinf(ang));
  }
}

// ------------------------------- MFMA GEMM (128^2) -------------------------
// C[M,N] = A[M,K] * Bt[N,K]^T, bf16 in. 128x128 tile, BK=32, 4 waves, 4x4
// 16x16x32 frags, global_load_lds(16) staging, 3-buffer distance-2 pipeline,
// T1 bijective XCD swizzle.
// MODE 0: float out to Cm.
// MODE 2: QKV epilogue — RoPE(q,k via lane-pair shfl + csT) + scatter to
//         qr/kr/vr [B,H,T,D]; q pre-scaled by 0.125*log2(e).
template <int MODE>
__global__ __launch_bounds__(256) void gemm_bt_kernel(const u16* __restrict__ A,
                                                      const u16* __restrict__ Bt,
                                                      float* __restrict__ Cm,
                                                      u16* __restrict__ qr,
                                                      u16* __restrict__ kr,
                                                      u16* __restrict__ vrp,
                                                      const float2* __restrict__ csT,
                                                      int M, int N, int K) {
  __shared__ u16 sA[3][128 * 32];
  __shared__ u16 sB[3][128 * 32];
  const int tid = threadIdx.x;
  const int lane = tid & 63;
  const int wv = tid >> 6;
  const int wr = wv >> 1, wc = wv & 1;
  const int l16 = lane & 15, lq = lane >> 4;

  // T1 XCD swizzle: dispatch idx flat -> work item (flat%8)*cpx + flat/8.
  const int gx = gridDim.x;
  const int nwg = gx * gridDim.y;
  const int flat = blockIdx.y * gx + blockIdx.x;
  const int swz = (flat & 7) * (nwg >> 3) + (flat >> 3);
  const int rowBase = (swz / gx) * 128;
  const int colBase = (swz % gx) * 128;

  f32x4 acc[4][4] = {};

  const int e0 = wv * 1024 + lane * 8;      // this lane's elem offset, chunk 0

#define GSTAGE(buf, kk)                                                          \
  {                                                                              \
    _Pragma("unroll")                                                            \
    for (int s = 0; s < 2; ++s) {                                                \
      int e = e0 + s * 512;                                                      \
      int r = e >> 5, ccc = e & 31;                                              \
      __builtin_amdgcn_global_load_lds(                                          \
          (const AS1 u32*)(A + (size_t)(rowBase + r) * K + (kk) + ccc),          \
          (AS3 u32*)&sA[buf][wv * 1024 + s * 512], 16, 0, 0);                    \
      __builtin_amdgcn_global_load_lds(                                          \
          (const AS1 u32*)(Bt + (size_t)(colBase + r) * K + (kk) + ccc),         \
          (AS3 u32*)&sB[buf][wv * 1024 + s * 512], 16, 0, 0);                    \
    }                                                                            \
  }

  const int NT = K >> 5;                 // K/32 tiles
  GSTAGE(0, 0);
  if (NT > 1) GSTAGE(1, 32);

  int cur = 0;
  for (int kt = 0; kt < NT; ++kt) {
    if (kt + 1 < NT) {
      asm volatile("s_waitcnt vmcnt(4)" ::: "memory");   // tile kt landed (own)
    } else {
      asm volatile("s_waitcnt vmcnt(0)" ::: "memory");   // final tile
    }
    __builtin_amdgcn_s_barrier();        // tile kt visible; k-1 reads done

    if (kt + 2 < NT) {
      int nb = cur + 2; if (nb >= 3) nb -= 3;
      GSTAGE(nb, (kt + 2) * 32);         // overlaps this iter's compute
    }

    bf16x8 af[4], bf[4];
    #pragma unroll
    for (int m = 0; m < 4; ++m)
      af[m] = u2b8(*(const u16x8*)&sA[cur][(wr * 64 + m * 16 + l16) * 32 + lq * 8]);
    #pragma unroll
    for (int n = 0; n < 4; ++n)
      bf[n] = u2b8(*(const u16x8*)&sB[cur][(wc * 64 + n * 16 + l16) * 32 + lq * 8]);
    __builtin_amdgcn_s_setprio(1);
    #pragma unroll
    for (int m = 0; m < 4; ++m)
      #pragma unroll
      for (int n = 0; n < 4; ++n)
        acc[m][n] = __builtin_amdgcn_mfma_f32_16x16x32_bf16(af[m], bf[n], acc[m][n], 0, 0, 0);
    __builtin_amdgcn_s_setprio(0);

    cur = (cur + 1 == 3) ? 0 : cur + 1;
  }
#undef GSTAGE

  // C/D layout (verified m89): col = lane&15, row = (lane>>4)*4 + reg
  if constexpr (MODE == 0) {
    #pragma unroll
    for (int m = 0; m < 4; ++m)
      #pragma unroll
      for (int n = 0; n < 4; ++n) {
        int row = rowBase + wr * 64 + m * 16 + lq * 4;
        int col = colBase + wc * 64 + n * 16 + l16;
        #pragma unroll
        for (int j = 0; j < 4; ++j)
          Cm[(size_t)(row + j) * N + col] = acc[m][n][j];
      }
  } else {
    // which: 0=q 1=k 2=v (block-uniform); head: uniform per (wave,n-range)
    const int which = colBase >> 10;
    const int head = ((colBase + wc * 64) >> 6) & 15;
    const float QSC = 0.125f * 1.44269504f;
    u16* const dst = (which == 0) ? qr : (which == 1) ? kr : vrp;
    #pragma unroll
    for (int m = 0; m < 4; ++m) {
      #pragma unroll
      for (int n = 0; n < 4; ++n) {
        const int d0 = n * 16 + l16;           // d within head (0..63)
        #pragma unroll
        for (int j = 0; j < 4; ++j) {
          int row = rowBase + wr * 64 + m * 16 + lq * 4 + j;
          int b = row >> 11, t = row & 2047;
          float v = acc[m][n][j];
          u16 outv;
          if (which == 2) {
            outv = f2b(v);
          } else {
            float p = __shfl_xor(v, 1);        // RoPE partner (d0^1)
            float2 cs = csT[t * 32 + (d0 >> 1)];
            float r = (l16 & 1) ? fmaf(p, cs.y, v * cs.x)    // odd:  xe*s + xo*c
                                : fmaf(-p, cs.y, v * cs.x);  // even: xe*c - xo*s
            if (which == 0) r *= QSC;
            outv = f2b(r);
          }
          dst[((size_t)(b * 16 + head) * 2048 + t) * 64 + d0] = outv;
        }
      }
    }
  }
}

// --------------------------- MFMA GEMM (64^2, out-proj) --------------------
// C[M,N] = A[M,K] * Bt[N,K]^T, float out. 64x64 tile, BK=32, 4 waves (2x2,
// each 32x32 = 2x2 frags). Same distance-2 / 3-buffer / counted-vmcnt pipeline
// as the 128^2 kernel, but 1 DMA per thread per operand per tile -> vmcnt(2).
// grid (N/64, M/64) = (16,64) = 1024 blocks = 4 blocks/CU (fixes out-proj's
// previous 1 block/CU). LDS 24KB. XCD swizzle (1024%8==0).
__global__ __launch_bounds__(256) void gemm64_kernel(const u16* __restrict__ A,
                                                     const u16* __restrict__ Bt,
                                                     float* __restrict__ Cm,
                                                     int M, int N, int K) {
  __shared__ u16 sA[3][64 * 32];
  __shared__ u16 sB[3][64 * 32];
  const int tid = threadIdx.x;
  const int lane = tid & 63;
  const int wv = tid >> 6;
  const int wr = wv >> 1, wc = wv & 1;
  const int l16 = lane & 15, lq = lane >> 4;

  const int gx = gridDim.x;
  const int nwg = gx * gridDim.y;
  const int flat = blockIdx.y * gx + blockIdx.x;
  const int swz = (flat & 7) * (nwg >> 3) + (flat >> 3);
  const int rowBase = (swz / gx) * 64;
  const int colBase = (swz % gx) * 64;

  f32x4 acc[2][2] = {};

  const int e0 = wv * 512 + lane * 8;       // this lane's elem offset (2048/tile)

#define GSTAGE64(buf, kk)                                                        \
  {                                                                              \
    int r = e0 >> 5, ccc = e0 & 31;                                              \
    __builtin_amdgcn_global_load_lds(                                            \
        (const AS1 u32*)(A + (size_t)(rowBase + r) * K + (kk) + ccc),            \
        (AS3 u32*)&sA[buf][wv * 512], 16, 0, 0);                                 \
    __builtin_amdgcn_global_load_lds(                                            \
        (const AS1 u32*)(Bt + (size_t)(colBase + r) * K + (kk) + ccc),           \
        (AS3 u32*)&sB[buf][wv * 512], 16, 0, 0);                                 \
  }

  const int NT = K >> 5;                 // K/32 tiles
  GSTAGE64(0, 0);
  if (NT > 1) GSTAGE64(1, 32);

  int cur = 0;
  for (int kt = 0; kt < NT; ++kt) {
    if (kt + 1 < NT) {
      asm volatile("s_waitcnt vmcnt(2)" ::: "memory");   // tile kt landed (own 2)
    } else {
      asm volatile("s_waitcnt vmcnt(0)" ::: "memory");   // final tile
    }
    __builtin_amdgcn_s_barrier();        // tile kt visible; kt-1 reads done

    if (kt + 2 < NT) {
      int nb = cur + 2; if (nb >= 3) nb -= 3;
      GSTAGE64(nb, (kt + 2) * 32);       // overlaps this iter's compute
    }

    bf16x8 af[2], bf[2];
    #pragma unroll
    for (int m = 0; m < 2; ++m)
      af[m] = u2b8(*(const u16x8*)&sA[cur][(wr * 32 + m * 16 + l16) * 32 + lq * 8]);
    #pragma unroll
    for (int n = 0; n < 2; ++n)
      bf[n] = u2b8(*(const u16x8*)&sB[cur][(wc * 32 + n * 16 + l16) * 32 + lq * 8]);
    __builtin_amdgcn_s_setprio(1);
    #pragma unroll
    for (int m = 0; m < 2; ++m)
      #pragma unroll
      for (int n = 0; n < 2; ++n)
        acc[m][n] = __builtin_amdgcn_mfma_f32_16x16x32_bf16(af[m], bf[n], acc[m][n], 0, 0, 0);
    __builtin_amdgcn_s_setprio(0);

    cur = (cur + 1 == 3) ? 0 : cur + 1;
  }
#undef GSTAGE64

  // C/D layout: col = lane&15, row = (lane>>4)*4 + reg
  #pragma unroll
  for (int m = 0; m < 2; ++m)
    #pragma unroll
    for (int n = 0; n < 2; ++n) {
      int row = rowBase + wr * 32 + m * 16 + lq * 4;
      int col = colBase + wc * 32 + n * 16 + l16;
      #pragma unroll
      for (int j = 0; j < 4; ++j)
        Cm[(size_t)(row + j) * N + col] = acc[m][n][j];
    }
}

// ------------------------- MFMA flash attention ----------------------------
// R9 config (proven fastest): 16 q-rows/wave, grid (32,32) descending, swapped
// QK^T, in-register P via k-slot permutation (V rows staged bit-permuted
// vrow=[b5 b2 b4 b3 b1 b0] so PV A-operand = own exp2'd registers), K staged
// by global_load_lds DMA into linear [64][64] with chunk swizzle (slot (r,c)
// holds chunk c^(r&7)), double buffer, T14 prefetch, ONE barrier per tile.
__global__ __launch_bounds__(256, 4) void attn_mfma_kernel(const u16* __restrict__ qr,
                                                           const u16* __restrict__ kr,
                                                           const u16* __restrict__ vr,
                                                           u16* __restrict__ ao) {
  constexpr int LDVT = 72;
  __shared__ u16 sK[2][64 * 64];                 // linear, chunk-swizzled
  __shared__ u16 sVt[2][64 * LDVT];              // sVt[buf][d][k-slot]

  const int tid = threadIdx.x;
  const int lane = tid & 63;
  const int w = tid >> 6;
  const int l16 = lane & 15, lq = lane >> 4;
  const int bh = blockIdx.x;
  const int qt = (int)gridDim.y - 1 - (int)blockIdx.y;   // long blocks first
  const int qbase = qt * 64;
  const size_t hb = (size_t)bh * (T_ * D_);

  // Q frags (pre-scaled bf16): rows qbase + w*16 + l16
  bf16x8 qv[2];
  #pragma unroll
  for (int dc = 0; dc < 2; ++dc) {
    int row = qbase + w * 16 + l16;
    qv[dc] = u2b8(*(const u16x8*)(qr + hb + (size_t)row * 64 + dc * 32 + lq * 8));
  }

  f32x4 o[4] = {};              // o[dt]: O[q=lq*4+j][d=dt*16+l16]
  float mrow = -1e30f;          // running max (log2 domain), row q=l16
  float lrow = 0.0f;            // per-lane partial denom, row q=l16

  // K DMA maps: wave w covers rows w*16 + s*8 + (lane>>3), chunk lane&7.
  const int krow0 = w * 16 + (lane >> 3);
  const int ksrc = ((lane & 7) ^ (lane >> 3)) * 8;   // elem offset in row
  // V staging maps (reg path)
  const int vkp = tid & 31;           // V slot-pair 0..31 (slots 2vkp, 2vkp+1)
  const int vdb = tid >> 5;           // V d-block 0..7
  const int vtr = ((vkp >> 4) & 1) * 32 + ((vkp >> 1) & 1) * 16 +
                  ((vkp >> 3) & 1) * 8 + ((vkp >> 2) & 1) * 4 + (vkp & 1) * 2;

  u16x8 rv0, rv1;
#define STAGEK(buf, k0s)                                                       \
  {                                                                            \
    _Pragma("unroll")                                                          \
    for (int s = 0; s < 2; ++s)                                                \
      __builtin_amdgcn_global_load_lds(                                        \
          (const AS1 u32*)(kr + hb + (size_t)((k0s) + krow0 + s * 8) * 64 + ksrc), \
          (AS3 u32*)&sK[buf][(w * 16 + s * 8) * 64], 16, 0, 0);                \
  }
#define LOADV(k0s)                                                             \
  {                                                                            \
    rv0 = *(const u16x8*)(vr + hb + (size_t)((k0s) + vtr) * 64 + vdb * 8);     \
    rv1 = *(const u16x8*)(vr + hb + (size_t)((k0s) + vtr + 1) * 64 + vdb * 8); \
  }
#define WRITEV(buf)                                                            \
  {                                                                            \
    _Pragma("unroll")                                                          \
    for (int u = 0; u < 8; ++u) {                                              \
      u16x2 pk; pk[0] = rv0[u]; pk[1] = rv1[u];                                \
      *(u16x2*)&sVt[buf][(vdb * 8 + u) * LDVT + 2 * vkp] = pk;                 \
    }                                                                          \
  }

  STAGEK(0, 0);
  LOADV(0);
  WRITEV(0);
  __syncthreads();               // drains vmcnt (K DMA) + LDS writes

  const int nt = qt + 1;
  int cur = 0;
  for (int it = 0; it < nt; ++it) {
    const int k0 = it * 64;
    const bool more = (it + 1 < nt);
    if (more) {
      STAGEK(cur ^ 1, k0 + 64);        // async DMA into other buffer
      LOADV(k0 + 64);                  // V prefetch into regs (T14)
    }

    // ---- QK^T (swapped): accs[kt][j] = S[q=l16][slot k0+kt*16+lq*4+j]
    f32x4 accs[4] = {};
    __builtin_amdgcn_s_setprio(1);
    #pragma unroll
    for (int kt = 0; kt < 4; ++kt) {
      int chy = ((lq) ^ (l16 & 7)) * 8;        // dc=0 chunk
      int chz = ((4 + lq) ^ (l16 & 7)) * 8;    // dc=1 chunk
      bf16x8 kf0 = u2b8(*(const u16x8*)&sK[cur][(kt * 16 + l16) * 64 + chy]);
      bf16x8 kf1 = u2b8(*(const u16x8*)&sK[cur][(kt * 16 + l16) * 64 + chz]);
      accs[kt] = __builtin_amdgcn_mfma_f32_16x16x32_bf16(kf0, qv[0], accs[kt], 0, 0, 0);
      accs[kt] = __builtin_amdgcn_mfma_f32_16x16x32_bf16(kf1, qv[1], accs[kt], 0, 0, 0);
    }
    __builtin_amdgcn_s_setprio(0);

    const int qrow = qbase + w * 16 + l16;
    if (k0 + 63 > qbase + w * 16) {      // wave-uniform: diagonal tile only
      #pragma unroll
      for (int kt = 0; kt < 4; ++kt)
        #pragma unroll
        for (int j = 0; j < 4; ++j)
          if (k0 + kt * 16 + lq * 4 + j > qrow) accs[kt][j] = -1e30f;
    }
    // row max for q=l16: depth-4 tree + 2 shfl (k spread across lq groups)
    float m0 = fmaxf(fmaxf(accs[0][0], accs[0][1]), fmaxf(accs[0][2], accs[0][3]));
    float m1 = fmaxf(fmaxf(accs[1][0], accs[1][1]), fmaxf(accs[1][2], accs[1][3]));
    float m2 = fmaxf(fmaxf(accs[2][0], accs[2][1]), fmaxf(accs[2][2], accs[2][3]));
    float m3 = fmaxf(fmaxf(accs[3][0], accs[3][1]), fmaxf(accs[3][2], accs[3][3]));
    float mx = fmaxf(fmaxf(m0, m1), fmaxf(m2, m3));
    mx = fmaxf(mx, __shfl_xor(mx, 16));
    mx = fmaxf(mx, __shfl_xor(mx, 32));

    if (!__all(mx <= mrow)) {            // defer-max: exact skip when no new max
      float mnew = fmaxf(mrow, mx);
      float corr = __builtin_amdgcn_exp2f(mrow - mnew);   // row q=l16
      lrow *= corr;
      mrow = mnew;
      // broadcast corr into D-row space (q=lq*4+j) before scaling O
      f32x4 corrv;
      #pragma unroll
      for (int j = 0; j < 4; ++j) corrv[j] = __shfl(corr, lq * 4 + j);
      #pragma unroll
      for (int dt = 0; dt < 4; ++dt) o[dt] *= corrv;
    }
    const float mu = mrow;
    // exp2 + pack: pb[kc][u] : u<4 <- slot kt=2kc, u>=4 <- kt=2kc+1
    bf16x8 pb[2];
    float lsum = 0.0f;
    #pragma unroll
    for (int kt = 0; kt < 4; ++kt) {
      #pragma unroll
      for (int j = 0; j < 4; ++j) {
        float p = __builtin_amdgcn_exp2f(accs[kt][j] - mu);
        lsum += p;
        pb[kt >> 1][(kt & 1) * 4 + j] = (__bf16)p;   // -> v_cvt_pk_bf16_f32
      }
    }
    lrow += lsum;

    // ---- PV: A-operand = own registers (slot perm); B from sVt ----
    __builtin_amdgcn_s_setprio(1);
    #pragma unroll
    for (int kc = 0; kc < 2; ++kc) {
      #pragma unroll
      for (int dt = 0; dt < 4; ++dt) {
        bf16x8 vt = u2b8(*(const u16x8*)&sVt[cur][(dt * 16 + l16) * LDVT + kc * 32 + lq * 8]);
        o[dt] = __builtin_amdgcn_mfma_f32_16x16x32_bf16(pb[kc], vt, o[dt], 0, 0, 0);
      }
    }
    __builtin_amdgcn_s_setprio(0);

    if (more) WRITEV(cur ^ 1);           // V^T into other buffer (reads were cur)
    __syncthreads();                     // one barrier/tile; drains K DMA too
    cur ^= 1;
  }

  // finalize: full row denom in l16-space, broadcast 1/l into D-row space.
  const int b = bh >> 4, h = bh & 15;
  float l = lrow;
  l += __shfl_xor(l, 16);
  l += __shfl_xor(l, 32);
  float linv = 1.0f / l;
  #pragma unroll
  for (int j = 0; j < 4; ++j) {
    float lj = __shfl(linv, lq * 4 + j);   // lane r (r<16) holds row r's denom
    int row = qbase + w * 16 + lq * 4 + j;
    u16* orow = ao + ((size_t)(b * T_ + row)) * C_ + h * 64;
    #pragma unroll
    for (int dt = 0; dt < 4; ++dt)
      orow[dt * 16 + l16] = f2b(o[dt][j] * lj);
  }
}

// ------------------------------- launcher ----------------------------------
// ws layout (bytes):                              size
//   xb     @ 0           bf16 x           8,388,608
//   wqkvT  @ 8388608     bf16 w_qkv^T     6,291,456
//   woutT  @ 14680064    bf16 w_out^T     2,097,152
//   qr     @ 41943040    bf16 [B,H,T,D]   8,388,608
//   kr     @ 50331648                     8,388,608
//   vr     @ 58720256                     8,388,608
//   ao     @ 67108864    bf16 attn out    8,388,608
//   csT    @ 75497472    f32x2 rope tbl     524,288
extern "C" void kernel_launch(void* const* d_in, const int* in_sizes, int n_in,
                              void* d_out, int out_size, void* d_ws, size_t ws_size,
                              hipStream_t stream) {
  const float* x     = (const float*)d_in[0];
  const float* w_qkv = (const float*)d_in[1];
  const float* w_out = (const float*)d_in[2];
  float* out = (float*)d_out;
  char* ws = (char*)d_ws;

  u16* xb     = (u16*)(ws + 0);
  u16* wqkvT  = (u16*)(ws + 8388608);
  u16* woutT  = (u16*)(ws + 14680064);
  u16* qr     = (u16*)(ws + 41943040);
  u16* kr     = (u16*)(ws + 50331648);
  u16* vr     = (u16*)(ws + 58720256);
  u16* ao     = (u16*)(ws + 67108864);
  float2* csT = (float2*)(ws + 75497472);

  prep_kernel<<<8448, 256, 0, stream>>>(x, w_qkv, w_out, xb, wqkvT, woutT, csT);
  gemm_bt_kernel<2><<<dim3(F_ / 128, M_ / 128), 256, 0, stream>>>(
      xb, wqkvT, nullptr, qr, kr, vr, (const float2*)csT, M_, F_, C_);
  attn_mfma_kernel<<<dim3(B_ * H_, T_ / 64), 256, 0, stream>>>(qr, kr, vr, ao);
  gemm64_kernel<<<dim3(C_ / 64, M_ / 64), 256, 0, stream>>>(ao, woutT, out, M_, C_, C_);
}